// Round 6
// baseline (471.579 us; speedup 1.0000x reference)
//
#include <hip/hip_runtime.h>

// RGCN pruned to the 2-hop cone of the first 1024 nodes.
// R6: single NORMAL-LAUNCH megakernel with software grid barriers
// (single-use atomic slots, zeroed by one small memset node). Occupancy
// verified at runtime; R4 10-kernel chain as fallback. 2 graph nodes.

#define N_NODES 100000
#define N_EDGES 400000
#define IN_DIM  768
#define HID     256
#define OUT_DIM 128
#define NREL    3
#define BATCH   1024
#define KCAT    1024   // HID*(NREL+1)
#define MSGW    768    // NREL*HID
#define CAP0    32768  // |S0| ~23K
#define CAP1    8192   // |S1| ~5K
#define ECAP1   32768  // edges into S1 ~20K
#define ECAP2   8192   // edges into S2 ~4.1K
#define NBAR    12     // barrier slots (9 used)

typedef __attribute__((ext_vector_type(8))) short bf16x8;
typedef __attribute__((ext_vector_type(4))) float f32x4;

static __device__ __forceinline__ int imin(int a, int b) { return a < b ? a : b; }

static __device__ __forceinline__ unsigned short f2bf(float f) {
    union { float f; unsigned int u; } v; v.f = f;
    unsigned int r = v.u + 0x7FFFu + ((v.u >> 16) & 1u);   // RNE
    return (unsigned short)(r >> 16);
}

struct Prm {
    const float* x; const int* ei; const int* et;
    const float *W1, *b1, *c1W, *c1root, *c1bias, *c2W, *c2root, *c2bias, *W2, *b2, *Wc, *bc;
    float* out;
    uint4* zp; int nz;
    int* bar;                     // NBAR slots, one per 64B line, pre-zeroed
    int *need1, *need0, *map1, *map0, *idx1, *idx0, *elist1, *elist2;
    int *n1ctr, *n0ctr, *ectr1, *ectr2;
    float *cnt1, *cnt2, *Amsg1, *Amsg2, *h0c, *h1c, *h2;
    unsigned short *w1s, *B1s, *B2s;
};

// ---- software grid barrier: single-use slot, device-scope, fail-fast ----
static __device__ __forceinline__ void gbar(int* bar, int slot) {
    __syncthreads();
    if (threadIdx.x == 0) {
        int* c = bar + slot * 16;            // one cacheline per slot
        __threadfence();                     // release: block's writes -> device
        atomicAdd(c, 1);                     // device-scope by default
        int nb = (int)gridDim.x;
        long spins = 0;
        while (__hip_atomic_load(c, __ATOMIC_ACQUIRE, __HIP_MEMORY_SCOPE_AGENT) < nb) {
            __builtin_amdgcn_s_sleep(2);
            if (++spins > (1L << 24)) break; // fail fast (wrong output) vs 600s hang
        }
        __threadfence();                     // acquire
    }
    __syncthreads();
}

// ---------------- device phase helpers (verified in R2-R4) ----------------

static __device__ void weight_prep_dev(const Prm& p, int gtid, int gstr) {
    const int P1n = (IN_DIM * HID) / 8, P2n = (KCAT * HID) / 8;
    for (int u = gtid; u < P1n + 2 * P2n; u += gstr) {
        unsigned int pk[4];
        if (u < P1n) {
            int base = u * 8;
            int j0 = base & 31, c = (base >> 5) & 255, s = base >> 13;
            #pragma unroll
            for (int q = 0; q < 4; q++) {
                unsigned short lo = f2bf(p.W1[((s * 32 + j0 + 2 * q) << 8) + c]);
                unsigned short hi = f2bf(p.W1[((s * 32 + j0 + 2 * q + 1) << 8) + c]);
                pk[q] = (unsigned int)lo | ((unsigned int)hi << 16);
            }
            *(uint4*)&p.w1s[base] = make_uint4(pk[0], pk[1], pk[2], pk[3]);
        } else {
            int which2 = (u - P1n) >= P2n;
            const float* root = which2 ? p.c2root : p.c1root;
            const float* Wr   = which2 ? p.c2W : p.c1W;
            unsigned short* dst = which2 ? p.B2s : p.B1s;
            int base = ((u - P1n) - (which2 ? P2n : 0)) * 8;
            int j0 = base & 31, c = (base >> 5) & 255, s = base >> 13;
            int k0 = s * 32 + j0;
            #pragma unroll
            for (int q = 0; q < 4; q++) {
                int ka = k0 + 2 * q, kb = ka + 1;
                float va = (ka < HID) ? root[(ka << 8) + c] : Wr[((ka - HID) << 8) + c];
                float vb = (kb < HID) ? root[(kb << 8) + c] : Wr[((kb - HID) << 8) + c];
                pk[q] = (unsigned int)f2bf(va) | ((unsigned int)f2bf(vb) << 16);
            }
            *(uint4*)&dst[base] = make_uint4(pk[0], pk[1], pk[2], pk[3]);
        }
    }
}

static __device__ void scatter_dev(const int* __restrict__ ei, const int* __restrict__ et,
                                   const int* __restrict__ elist, const int* __restrict__ ectr, int ecap,
                                   const int* __restrict__ mapSrc, const int* __restrict__ mapDst,
                                   const float* __restrict__ hsrc,
                                   float* __restrict__ Amsg, float* __restrict__ cnt,
                                   int cntStride, int gtid, int gstr) {
    int n = imin(*ectr, ecap);
    int tot = n * 64;
    for (int g = gtid; g < tot; g += gstr) {
        int ii = g >> 6, lane = g & 63;
        int e = elist[ii];
        int d = ei[N_EDGES + e];
        int row = mapDst ? mapDst[d] : d;
        if (row < 0) continue;
        int s = mapSrc[ei[e]];
        if (s < 0) continue;
        int r = et[e];
        float4 v = *(const float4*)(hsrc + (size_t)s * HID + lane * 4);
        float* dp = Amsg + (size_t)row * MSGW + (size_t)r * HID + lane * 4;
        atomicAdd(dp + 0, v.x);
        atomicAdd(dp + 1, v.y);
        atomicAdd(dp + 2, v.z);
        atomicAdd(dp + 3, v.w);
        if (lane == 0) atomicAdd(cnt + (size_t)r * cntStride + row, 1.0f);
    }
}

static __device__ void gemm1_tile(const float* __restrict__ x, const int* __restrict__ idx0,
                                  const unsigned short* __restrict__ w1s, const float* __restrict__ b1,
                                  float* __restrict__ h0c, int bm, int M,
                                  unsigned short (*As)[40], unsigned short (*Bs)[40]) {
    int tid = threadIdx.x;
    int w = tid >> 6, lane = tid & 63;
    int l16 = lane & 15, lhi = lane >> 4;
    int ar = tid >> 2, ac = tid & 3;
    int gr = idx0[imin(bm + ar, M - 1)];
    const float* aptr = x + (size_t)gr * IN_DIM + ac * 8;

    f32x4 acc[16];
    #pragma unroll
    for (int i = 0; i < 16; i++) acc[i] = (f32x4)0.0f;

    for (int k0 = 0; k0 < IN_DIM; k0 += 32) {
        float4 a0 = *(const float4*)(aptr + k0);
        float4 a1 = *(const float4*)(aptr + k0 + 4);
        unsigned int p0 = (unsigned int)f2bf(a0.x) | ((unsigned int)f2bf(a0.y) << 16);
        unsigned int p1 = (unsigned int)f2bf(a0.z) | ((unsigned int)f2bf(a0.w) << 16);
        unsigned int p2 = (unsigned int)f2bf(a1.x) | ((unsigned int)f2bf(a1.y) << 16);
        unsigned int p3 = (unsigned int)f2bf(a1.z) | ((unsigned int)f2bf(a1.w) << 16);
        *(uint4*)&As[ar][ac * 8] = make_uint4(p0, p1, p2, p3);

        const uint4* bsrc = (const uint4*)(w1s + ((size_t)(k0 >> 5) * 256 + tid) * 32);
        int bswz = (tid >> 3) & 3;
        uint4 b0 = bsrc[0], b1v = bsrc[1], b2 = bsrc[2], b3 = bsrc[3];
        *(uint4*)&Bs[tid][(0 ^ bswz) * 8] = b0;
        *(uint4*)&Bs[tid][(1 ^ bswz) * 8] = b1v;
        *(uint4*)&Bs[tid][(2 ^ bswz) * 8] = b2;
        *(uint4*)&Bs[tid][(3 ^ bswz) * 8] = b3;
        __syncthreads();

        bf16x8 af = *(bf16x8*)&As[w * 16 + l16][lhi * 8];
        #pragma unroll
        for (int f = 0; f < 16; f++) {
            int col = f * 16 + l16;
            bf16x8 bf = *(bf16x8*)&Bs[col][(lhi ^ ((col >> 3) & 3)) * 8];
            acc[f] = __builtin_amdgcn_mfma_f32_16x16x32_bf16(af, bf, acc[f], 0, 0, 0);
        }
        __syncthreads();
    }

    #pragma unroll
    for (int f = 0; f < 16; f++) {
        int col = f * 16 + l16;
        float bb = b1[col];
        #pragma unroll
        for (int reg = 0; reg < 4; reg++) {
            int row = bm + w * 16 + lhi * 4 + reg;
            if (row < M) h0c[(size_t)row * HID + col] = fmaxf(acc[f][reg] + bb, 0.0f);
        }
    }
}

static __device__ void conv_tile(const float* __restrict__ hsrc,
                                 const int* __restrict__ idx, const int* __restrict__ map,
                                 const float* __restrict__ Amsg,
                                 const float* __restrict__ cnt, int cntStride,
                                 const unsigned short* __restrict__ Bt, const float* __restrict__ bias,
                                 float* __restrict__ Cout, int bm, int M,
                                 unsigned short (*As)[40], unsigned short (*Bs)[40]) {
    int tid = threadIdx.x;
    int w = tid >> 6, lane = tid & 63;
    int l16 = lane & 15, lhi = lane >> 4;
    int ar = tid >> 2, ac = tid & 3;
    int row = imin(bm + ar, M - 1);
    int node = idx ? idx[row] : row;
    int grow = map[node]; if (grow < 0) grow = 0;
    const float* rootp = hsrc + (size_t)grow * HID + ac * 8;
    const float* msgp  = Amsg + (size_t)row * MSGW + ac * 8;
    float sc[NREL];
    #pragma unroll
    for (int r = 0; r < NREL; r++)
        sc[r] = 1.0f / fmaxf(cnt[(size_t)r * cntStride + row], 1.0f);

    f32x4 acc[16];
    #pragma unroll
    for (int i = 0; i < 16; i++) acc[i] = (f32x4)0.0f;

    for (int k0 = 0; k0 < KCAT; k0 += 32) {
        float4 a0, a1;
        if (k0 < HID) {
            a0 = *(const float4*)(rootp + k0);
            a1 = *(const float4*)(rootp + k0 + 4);
        } else {
            float s = sc[(k0 - HID) >> 8];
            a0 = *(const float4*)(msgp + (k0 - HID));
            a1 = *(const float4*)(msgp + (k0 - HID) + 4);
            a0.x *= s; a0.y *= s; a0.z *= s; a0.w *= s;
            a1.x *= s; a1.y *= s; a1.z *= s; a1.w *= s;
        }
        unsigned int p0 = (unsigned int)f2bf(a0.x) | ((unsigned int)f2bf(a0.y) << 16);
        unsigned int p1 = (unsigned int)f2bf(a0.z) | ((unsigned int)f2bf(a0.w) << 16);
        unsigned int p2 = (unsigned int)f2bf(a1.x) | ((unsigned int)f2bf(a1.y) << 16);
        unsigned int p3 = (unsigned int)f2bf(a1.z) | ((unsigned int)f2bf(a1.w) << 16);
        *(uint4*)&As[ar][ac * 8] = make_uint4(p0, p1, p2, p3);

        const uint4* bsrc = (const uint4*)(Bt + ((size_t)(k0 >> 5) * 256 + tid) * 32);
        int bswz = (tid >> 3) & 3;
        uint4 b0 = bsrc[0], b1v = bsrc[1], b2 = bsrc[2], b3 = bsrc[3];
        *(uint4*)&Bs[tid][(0 ^ bswz) * 8] = b0;
        *(uint4*)&Bs[tid][(1 ^ bswz) * 8] = b1v;
        *(uint4*)&Bs[tid][(2 ^ bswz) * 8] = b2;
        *(uint4*)&Bs[tid][(3 ^ bswz) * 8] = b3;
        __syncthreads();

        bf16x8 af = *(bf16x8*)&As[w * 16 + l16][lhi * 8];
        #pragma unroll
        for (int f = 0; f < 16; f++) {
            int col = f * 16 + l16;
            bf16x8 bf = *(bf16x8*)&Bs[col][(lhi ^ ((col >> 3) & 3)) * 8];
            acc[f] = __builtin_amdgcn_mfma_f32_16x16x32_bf16(af, bf, acc[f], 0, 0, 0);
        }
        __syncthreads();
    }

    #pragma unroll
    for (int f = 0; f < 16; f++) {
        int col = f * 16 + l16;
        float bb = bias[col];
        #pragma unroll
        for (int reg = 0; reg < 4; reg++) {
            int r = bm + w * 16 + lhi * 4 + reg;
            if (r < M) Cout[(size_t)r * HID + col] = acc[f][reg] + bb;
        }
    }
}

static __device__ void lin2_tile(const float* __restrict__ h2, const float* __restrict__ W2,
                                 const float* __restrict__ b2, const float* __restrict__ Wc,
                                 const float* __restrict__ bc, float* __restrict__ out, int bm,
                                 float (*Asf)[36], float (*Bsf)[132]) {
    int tid = threadIdx.x;
    int tx = tid & 15, ty = tid >> 4;
    int brow = tid >> 4, bch = tid & 15;

    float acc[2][8] = {};

    for (int k0 = 0; k0 < HID; k0 += 16) {
        if (tid < 128) {
            int arow = tid >> 2, ach = tid & 3;
            float4 av = *(const float4*)(h2 + (size_t)(bm + arow) * HID + k0 + ach * 4);
            Asf[ach * 4 + 0][arow] = av.x;
            Asf[ach * 4 + 1][arow] = av.y;
            Asf[ach * 4 + 2][arow] = av.z;
            Asf[ach * 4 + 3][arow] = av.w;
        }
        const float* bp = W2 + (size_t)(k0 + brow) * OUT_DIM;
        *(float4*)&Bsf[brow][bch * 4]      = *(const float4*)(bp + bch * 4);
        *(float4*)&Bsf[brow][64 + bch * 4] = *(const float4*)(bp + 64 + bch * 4);
        __syncthreads();
        #pragma unroll
        for (int k = 0; k < 16; k++) {
            float a0 = Asf[k][ty * 2], a1 = Asf[k][ty * 2 + 1];
            float4 b0 = *(const float4*)&Bsf[k][tx * 8];
            float4 b1 = *(const float4*)&Bsf[k][tx * 8 + 4];
            acc[0][0] += a0 * b0.x; acc[0][1] += a0 * b0.y; acc[0][2] += a0 * b0.z; acc[0][3] += a0 * b0.w;
            acc[0][4] += a0 * b1.x; acc[0][5] += a0 * b1.y; acc[0][6] += a0 * b1.z; acc[0][7] += a0 * b1.w;
            acc[1][0] += a1 * b0.x; acc[1][1] += a1 * b0.y; acc[1][2] += a1 * b0.z; acc[1][3] += a1 * b0.w;
            acc[1][4] += a1 * b1.x; acc[1][5] += a1 * b1.y; acc[1][6] += a1 * b1.z; acc[1][7] += a1 * b1.w;
        }
        __syncthreads();
    }

    float s0[2] = {0.f, 0.f}, s1[2] = {0.f, 0.f};
    #pragma unroll
    for (int j = 0; j < 8; j++) {
        int col = tx * 8 + j;
        float w0 = Wc[col * 2 + 0], w1 = Wc[col * 2 + 1];
        float bb = b2[col];
        #pragma unroll
        for (int i = 0; i < 2; i++) {
            float h = fmaxf(acc[i][j] + bb, 0.0f);
            s0[i] += h * w0;
            s1[i] += h * w1;
        }
    }
    #pragma unroll
    for (int o = 1; o <= 8; o <<= 1) {
        #pragma unroll
        for (int i = 0; i < 2; i++) {
            s0[i] += __shfl_xor(s0[i], o);
            s1[i] += __shfl_xor(s1[i], o);
        }
    }
    if (tx == 0) {
        #pragma unroll
        for (int i = 0; i < 2; i++) {
            int row = bm + ty * 2 + i;
            out[row * 2 + 0] = s0[i] + bc[0];
            out[row * 2 + 1] = s1[i] + bc[1];
        }
    }
}

// ---------------- the megakernel (normal launch, software barriers) ----------------

__global__ __launch_bounds__(256, 2) void mega(Prm p) {
    __shared__ __align__(16) char sm[(64 * 40 + 256 * 40) * 2];   // 25600 B
    unsigned short (*As)[40] = (unsigned short(*)[40])sm;
    unsigned short (*Bs)[40] = (unsigned short(*)[40])(sm + 64 * 40 * 2);

    const int tid  = threadIdx.x;
    const int gtid = blockIdx.x * 256 + tid;
    const int gstr = gridDim.x * 256;

    // P0: zero accumulation block + bf16 weight prep
    {
        uint4 z = make_uint4(0u, 0u, 0u, 0u);
        for (int t = gtid; t < p.nz; t += gstr) p.zp[t] = z;
        weight_prep_dev(p, gtid, gstr);
    }
    gbar(p.bar, 0);

    // P1: mark sources of edges into S2, build elist2
    for (int e = gtid; e < N_EDGES; e += gstr) {
        if (p.ei[N_EDGES + e] < BATCH) {
            p.need1[p.ei[e]] = 1;   // benign same-value race
            int q = atomicAdd(p.ectr2, 1);
            if (q < ECAP2) p.elist2[q] = e;
        }
    }
    gbar(p.bar, 1);

    // P2: mark sources of edges into S1, build elist1
    for (int e = gtid; e < N_EDGES; e += gstr) {
        int d = p.ei[N_EDGES + e];
        if (d < BATCH || p.need1[d]) {
            p.need0[p.ei[e]] = 1;
            int q = atomicAdd(p.ectr1, 1);
            if (q < ECAP1) p.elist1[q] = e;
        }
    }
    gbar(p.bar, 2);

    // P3: compact S1 and S0
    for (int i = gtid; i < N_NODES; i += gstr) {
        int f1 = (i < BATCH) | p.need1[i];
        int f0 = f1 | p.need0[i];
        if (f1) {
            int q = atomicAdd(p.n1ctr, 1);
            if (q < CAP1) { p.idx1[q] = i; p.map1[i] = q; } else p.map1[i] = -1;
        } else p.map1[i] = -1;
        if (f0) {
            int q = atomicAdd(p.n0ctr, 1);
            if (q < CAP0) { p.idx0[q] = i; p.map0[i] = q; } else p.map0[i] = -1;
        } else p.map0[i] = -1;
    }
    gbar(p.bar, 3);

    // P4: h0c = relu(x[S0] @ W1 + b1)
    {
        int M = imin(*p.n0ctr, CAP0);
        int nt = (M + 63) >> 6;
        for (int t = blockIdx.x; t < nt; t += gridDim.x)
            gemm1_tile(p.x, p.idx0, p.w1s, p.b1, p.h0c, t * 64, M, As, Bs);
    }
    gbar(p.bar, 4);

    // P5: scatter messages for conv1
    scatter_dev(p.ei, p.et, p.elist1, p.ectr1, ECAP1, p.map0, p.map1, p.h0c,
                p.Amsg1, p.cnt1, CAP1, gtid, gstr);
    gbar(p.bar, 5);

    // P6: conv1
    {
        int M = imin(*p.n1ctr, CAP1);
        int nt = (M + 63) >> 6;
        for (int t = blockIdx.x; t < nt; t += gridDim.x)
            conv_tile(p.h0c, p.idx1, p.map0, p.Amsg1, p.cnt1, CAP1,
                      p.B1s, p.c1bias, p.h1c, t * 64, M, As, Bs);
    }
    gbar(p.bar, 6);

    // P7: scatter messages for conv2
    scatter_dev(p.ei, p.et, p.elist2, p.ectr2, ECAP2, p.map1, nullptr, p.h1c,
                p.Amsg2, p.cnt2, BATCH, gtid, gstr);
    gbar(p.bar, 7);

    // P8: conv2 (rows = node ids 0..1023)
    for (int t = blockIdx.x; t < BATCH / 64; t += gridDim.x)
        conv_tile(p.h1c, nullptr, p.map1, p.Amsg2, p.cnt2, BATCH,
                  p.B2s, p.c2bias, p.h2, t * 64, BATCH, As, Bs);
    gbar(p.bar, 8);

    // P9: logits = relu(h2 @ W2 + b2) @ Wc + bc
    {
        float (*Asf)[36]  = (float(*)[36])sm;
        float (*Bsf)[132] = (float(*)[132])(sm + 16 * 36 * 4);
        for (int t = blockIdx.x; t < BATCH / 32; t += gridDim.x)
            lin2_tile(p.h2, p.W2, p.b2, p.Wc, p.bc, p.out, t * 32, Asf, Bsf);
    }
}

// ---------------- fallback chain (R4 kernels), used only if occupancy query fails ----------------

__global__ void fb_zero_prep(Prm p) {
    int t = blockIdx.x * blockDim.x + threadIdx.x;
    if (t < p.nz) { p.zp[t] = make_uint4(0u, 0u, 0u, 0u); return; }
    weight_prep_dev(p, t - p.nz, 1 << 30);
}
__global__ void fb_mark1c(Prm p) {
    int e = blockIdx.x * blockDim.x + threadIdx.x;
    if (e >= N_EDGES) return;
    if (p.ei[N_EDGES + e] < BATCH) {
        p.need1[p.ei[e]] = 1;
        int q = atomicAdd(p.ectr2, 1);
        if (q < ECAP2) p.elist2[q] = e;
    }
}
__global__ void fb_mark0c(Prm p) {
    int e = blockIdx.x * blockDim.x + threadIdx.x;
    if (e >= N_EDGES) return;
    int d = p.ei[N_EDGES + e];
    if (d < BATCH || p.need1[d]) {
        p.need0[p.ei[e]] = 1;
        int q = atomicAdd(p.ectr1, 1);
        if (q < ECAP1) p.elist1[q] = e;
    }
}
__global__ void fb_compact(Prm p) {
    int i = blockIdx.x * blockDim.x + threadIdx.x;
    if (i >= N_NODES) return;
    int f1 = (i < BATCH) | p.need1[i];
    int f0 = f1 | p.need0[i];
    if (f1) {
        int q = atomicAdd(p.n1ctr, 1);
        if (q < CAP1) { p.idx1[q] = i; p.map1[i] = q; } else p.map1[i] = -1;
    } else p.map1[i] = -1;
    if (f0) {
        int q = atomicAdd(p.n0ctr, 1);
        if (q < CAP0) { p.idx0[q] = i; p.map0[i] = q; } else p.map0[i] = -1;
    } else p.map0[i] = -1;
}
__global__ __launch_bounds__(256) void fb_gemm1(Prm p) {
    __shared__ unsigned short As[64][40];
    __shared__ unsigned short Bs[256][40];
    int M = imin(*p.n0ctr, CAP0);
    int bm = blockIdx.x * 64;
    if (bm >= M) return;
    gemm1_tile(p.x, p.idx0, p.w1s, p.b1, p.h0c, bm, M, As, Bs);
}
__global__ void fb_scatter1(Prm p) {
    int g = blockIdx.x * blockDim.x + threadIdx.x;
    scatter_dev(p.ei, p.et, p.elist1, p.ectr1, ECAP1, p.map0, p.map1, p.h0c,
                p.Amsg1, p.cnt1, CAP1, g, 1 << 30);
}
__global__ __launch_bounds__(256) void fb_conv1(Prm p) {
    __shared__ unsigned short As[64][40];
    __shared__ unsigned short Bs[256][40];
    int M = imin(*p.n1ctr, CAP1);
    int bm = blockIdx.x * 64;
    if (bm >= M) return;
    conv_tile(p.h0c, p.idx1, p.map0, p.Amsg1, p.cnt1, CAP1, p.B1s, p.c1bias, p.h1c, bm, M, As, Bs);
}
__global__ void fb_scatter2(Prm p) {
    int g = blockIdx.x * blockDim.x + threadIdx.x;
    scatter_dev(p.ei, p.et, p.elist2, p.ectr2, ECAP2, p.map1, nullptr, p.h1c,
                p.Amsg2, p.cnt2, BATCH, g, 1 << 30);
}
__global__ __launch_bounds__(256) void fb_conv2(Prm p) {
    __shared__ unsigned short As[64][40];
    __shared__ unsigned short Bs[256][40];
    conv_tile(p.h1c, nullptr, p.map1, p.Amsg2, p.cnt2, BATCH, p.B2s, p.c2bias, p.h2,
              blockIdx.x * 64, BATCH, As, Bs);
}
__global__ __launch_bounds__(256) void fb_lin2(Prm p) {
    __shared__ float Asf[16][36];
    __shared__ float Bsf[16][132];
    lin2_tile(p.h2, p.W2, p.b2, p.Wc, p.bc, p.out, blockIdx.x * 32, Asf, Bsf);
}

// ---------------- host ----------------

extern "C" void kernel_launch(void* const* d_in, const int* in_sizes, int n_in,
                              void* d_out, int out_size, void* d_ws, size_t ws_size,
                              hipStream_t stream) {
    Prm p;
    p.x      = (const float*)d_in[0];
    p.ei     = (const int*)d_in[1];
    p.et     = (const int*)d_in[2];
    p.W1     = (const float*)d_in[4];
    p.b1     = (const float*)d_in[5];
    p.c1W    = (const float*)d_in[6];
    p.c1root = (const float*)d_in[7];
    p.c1bias = (const float*)d_in[8];
    p.c2W    = (const float*)d_in[9];
    p.c2root = (const float*)d_in[10];
    p.c2bias = (const float*)d_in[11];
    p.W2     = (const float*)d_in[12];
    p.b2     = (const float*)d_in[13];
    p.Wc     = (const float*)d_in[14];
    p.bc     = (const float*)d_in[15];
    p.out    = (float*)d_out;

    char* ws = (char*)d_ws;
    size_t off = 0;
    auto alloc = [&](size_t bytes) -> char* {
        char* q = ws + off;
        off = (off + bytes + 255) & ~(size_t)255;
        return q;
    };

    // barrier slots (own region, zeroed by memset node each call)
    p.bar = (int*)alloc(NBAR * 64);

    // zero block (zeroed in-kernel by P0): ctrs | cnt1 | cnt2 | need1 | need0 | Amsg1 | Amsg2
    size_t zb_ctr   = 16;
    size_t zb_cnt1  = (size_t)NREL * CAP1 * 4;
    size_t zb_cnt2  = (size_t)NREL * BATCH * 4;
    size_t zb_need  = (size_t)N_NODES * 4;
    size_t zb_amsg1 = (size_t)CAP1 * MSGW * 4;
    size_t zb_amsg2 = (size_t)BATCH * MSGW * 4;
    size_t zbytes = zb_ctr + zb_cnt1 + zb_cnt2 + 2 * zb_need + zb_amsg1 + zb_amsg2;
    char* zblock = alloc(zbytes);
    p.zp    = (uint4*)zblock;
    p.nz    = (int)((zbytes + 15) / 16);
    p.n1ctr = (int*)zblock;
    p.n0ctr = p.n1ctr + 1;
    p.ectr1 = p.n1ctr + 2;
    p.ectr2 = p.n1ctr + 3;
    p.cnt1  = (float*)(zblock + zb_ctr);
    p.cnt2  = (float*)(zblock + zb_ctr + zb_cnt1);
    p.need1 = (int*)(zblock + zb_ctr + zb_cnt1 + zb_cnt2);
    p.need0 = (int*)((char*)p.need1 + zb_need);
    p.Amsg1 = (float*)((char*)p.need0 + zb_need);
    p.Amsg2 = (float*)((char*)p.Amsg1 + zb_amsg1);

    p.map1   = (int*)alloc(N_NODES * 4);
    p.map0   = (int*)alloc(N_NODES * 4);
    p.idx1   = (int*)alloc(CAP1 * 4);
    p.idx0   = (int*)alloc(CAP0 * 4);
    p.elist1 = (int*)alloc(ECAP1 * 4);
    p.elist2 = (int*)alloc(ECAP2 * 4);
    p.h0c    = (float*)alloc((size_t)CAP0 * HID * 4);
    p.h1c    = (float*)alloc((size_t)CAP1 * HID * 4);
    p.h2     = (float*)alloc((size_t)BATCH * HID * 4);
    p.w1s    = (unsigned short*)alloc((size_t)IN_DIM * HID * 2);
    p.B1s    = (unsigned short*)alloc((size_t)KCAT * HID * 2);
    p.B2s    = (unsigned short*)alloc((size_t)KCAT * HID * 2);
    (void)ws_size; (void)in_sizes; (void)n_in; (void)out_size;

    // node 1: zero the barrier slots
    hipMemsetAsync(p.bar, 0, NBAR * 64, stream);

    // co-residency check (pure query; capture-safe, deterministic)
    int occ = 0;
    hipError_t qe = hipOccupancyMaxActiveBlocksPerMultiprocessor(&occ, mega, 256, 0);

    if (qe == hipSuccess && occ >= 1) {
        int nblk = (occ >= 2) ? 512 : 256;   // grid <= occ * 256 CUs -> all co-resident
        // node 2: the whole pipeline
        mega<<<dim3(nblk), dim3(256), 0, stream>>>(p);
    } else {
        // fallback: R4-style 10-kernel chain (known-good, 408us)
        const int NB = 256;
        int prep_threads = (IN_DIM * HID) / 8 + 2 * (KCAT * HID) / 8;
        int zp_total = p.nz + prep_threads;
        fb_zero_prep<<<dim3((zp_total + NB - 1) / NB), NB, 0, stream>>>(p);
        fb_mark1c<<<dim3((N_EDGES + NB - 1) / NB), NB, 0, stream>>>(p);
        fb_mark0c<<<dim3((N_EDGES + NB - 1) / NB), NB, 0, stream>>>(p);
        fb_compact<<<dim3((N_NODES + NB - 1) / NB), NB, 0, stream>>>(p);
        fb_gemm1<<<dim3(CAP0 / 64), NB, 0, stream>>>(p);
        fb_scatter1<<<dim3(ECAP1 * 64 / NB), NB, 0, stream>>>(p);
        fb_conv1<<<dim3(CAP1 / 64), NB, 0, stream>>>(p);
        fb_scatter2<<<dim3(ECAP2 * 64 / NB), NB, 0, stream>>>(p);
        fb_conv2<<<dim3(BATCH / 64), NB, 0, stream>>>(p);
        fb_lin2<<<dim3(BATCH / 32), NB, 0, stream>>>(p);
    }
}

// Round 7
// 467.908 us; speedup vs baseline: 1.0078x; 1.0078x over previous
//
#include <hip/hip_runtime.h>

// RGCN pruned to the 2-hop cone of the first 1024 nodes.
// R7: megakernel with DISTRIBUTED software barriers (64 lines/slot, 8
// contenders per line, wave-parallel spin) replacing R6's single-line
// barrier (~35us each, measured via VALUBusy=1.2%). Flags/ctr zeroing moved
// to the host memset node; weight-prep and Amsg-zero folded into mark phases.
// 2 graph nodes, 9 phases, 8 barriers.

#define N_NODES 100000
#define N_EDGES 400000
#define IN_DIM  768
#define HID     256
#define OUT_DIM 128
#define NREL    3
#define BATCH   1024
#define KCAT    1024   // HID*(NREL+1)
#define MSGW    768    // NREL*HID
#define CAP0    32768  // |S0| ~23K
#define CAP1    8192   // |S1| ~5K
#define ECAP1   32768  // edges into S1 ~20K
#define ECAP2   8192   // edges into S2 ~4.1K
#define NBAR    9      // barrier slots
#define BLINES  64     // cachelines per barrier slot

typedef __attribute__((ext_vector_type(8))) short bf16x8;
typedef __attribute__((ext_vector_type(4))) float f32x4;

static __device__ __forceinline__ int imin(int a, int b) { return a < b ? a : b; }

static __device__ __forceinline__ unsigned short f2bf(float f) {
    union { float f; unsigned int u; } v; v.f = f;
    unsigned int r = v.u + 0x7FFFu + ((v.u >> 16) & 1u);   // RNE
    return (unsigned short)(r >> 16);
}

struct Prm {
    const float* x; const int* ei; const int* et;
    const float *W1, *b1, *c1W, *c1root, *c1bias, *c2W, *c2root, *c2bias, *W2, *b2, *Wc, *bc;
    float* out;
    uint4* zp; int nz;            // Amsg region (zeroed in-kernel, P2)
    int* bar;                     // NBAR slots x 64 lines x 64B, pre-zeroed by memset
    int *need1, *need0, *map1, *map0, *idx1, *idx0, *elist1, *elist2;
    int *n1ctr, *n0ctr, *ectr1, *ectr2;
    float *cnt1, *cnt2, *Amsg1, *Amsg2, *h0c, *h1c, *h2;
    unsigned short *w1s, *B1s, *B2s;
};

// ---- distributed grid barrier: 64 lines/slot, 8 adders/line at grid=512 ----
// requires gridDim.x to be a multiple of 64.
static __device__ __forceinline__ void gbar(int* bar, int slot) {
    __syncthreads();
    int* base = bar + slot * (BLINES * 16);
    if (threadIdx.x == 0) {
        __threadfence();                                  // release block's writes
        atomicAdd(base + (blockIdx.x & (BLINES - 1)) * 16, 1);
    }
    if (threadIdx.x < BLINES) {
        int target = (int)(gridDim.x >> 6);               // blocks per line
        int* line = base + threadIdx.x * 16;
        long spins = 0;
        while (__hip_atomic_load(line, __ATOMIC_ACQUIRE, __HIP_MEMORY_SCOPE_AGENT) < target) {
            __builtin_amdgcn_s_sleep(8);
            if (++spins > (1L << 20)) break;              // fail fast, not hang
        }
        __threadfence();                                  // acquire side
    }
    __syncthreads();
}

// ---------------- device phase helpers (verified R2-R6) ----------------

static __device__ void weight_prep_dev(const Prm& p, int gtid, int gstr) {
    const int P1n = (IN_DIM * HID) / 8, P2n = (KCAT * HID) / 8;
    for (int u = gtid; u < P1n + 2 * P2n; u += gstr) {
        unsigned int pk[4];
        if (u < P1n) {
            int base = u * 8;
            int j0 = base & 31, c = (base >> 5) & 255, s = base >> 13;
            #pragma unroll
            for (int q = 0; q < 4; q++) {
                unsigned short lo = f2bf(p.W1[((s * 32 + j0 + 2 * q) << 8) + c]);
                unsigned short hi = f2bf(p.W1[((s * 32 + j0 + 2 * q + 1) << 8) + c]);
                pk[q] = (unsigned int)lo | ((unsigned int)hi << 16);
            }
            *(uint4*)&p.w1s[base] = make_uint4(pk[0], pk[1], pk[2], pk[3]);
        } else {
            int which2 = (u - P1n) >= P2n;
            const float* root = which2 ? p.c2root : p.c1root;
            const float* Wr   = which2 ? p.c2W : p.c1W;
            unsigned short* dst = which2 ? p.B2s : p.B1s;
            int base = ((u - P1n) - (which2 ? P2n : 0)) * 8;
            int j0 = base & 31, c = (base >> 5) & 255, s = base >> 13;
            int k0 = s * 32 + j0;
            #pragma unroll
            for (int q = 0; q < 4; q++) {
                int ka = k0 + 2 * q, kb = ka + 1;
                float va = (ka < HID) ? root[(ka << 8) + c] : Wr[((ka - HID) << 8) + c];
                float vb = (kb < HID) ? root[(kb << 8) + c] : Wr[((kb - HID) << 8) + c];
                pk[q] = (unsigned int)f2bf(va) | ((unsigned int)f2bf(vb) << 16);
            }
            *(uint4*)&dst[base] = make_uint4(pk[0], pk[1], pk[2], pk[3]);
        }
    }
}

static __device__ void scatter_dev(const int* __restrict__ ei, const int* __restrict__ et,
                                   const int* __restrict__ elist, const int* __restrict__ ectr, int ecap,
                                   const int* __restrict__ mapSrc, const int* __restrict__ mapDst,
                                   const float* __restrict__ hsrc,
                                   float* __restrict__ Amsg, float* __restrict__ cnt,
                                   int cntStride, int gtid, int gstr) {
    int n = imin(*ectr, ecap);
    int tot = n * 64;
    for (int g = gtid; g < tot; g += gstr) {
        int ii = g >> 6, lane = g & 63;
        int e = elist[ii];
        int d = ei[N_EDGES + e];
        int row = mapDst ? mapDst[d] : d;
        if (row < 0) continue;
        int s = mapSrc[ei[e]];
        if (s < 0) continue;
        int r = et[e];
        float4 v = *(const float4*)(hsrc + (size_t)s * HID + lane * 4);
        float* dp = Amsg + (size_t)row * MSGW + (size_t)r * HID + lane * 4;
        atomicAdd(dp + 0, v.x);
        atomicAdd(dp + 1, v.y);
        atomicAdd(dp + 2, v.z);
        atomicAdd(dp + 3, v.w);
        if (lane == 0) atomicAdd(cnt + (size_t)r * cntStride + row, 1.0f);
    }
}

static __device__ void gemm1_tile(const float* __restrict__ x, const int* __restrict__ idx0,
                                  const unsigned short* __restrict__ w1s, const float* __restrict__ b1,
                                  float* __restrict__ h0c, int bm, int M,
                                  unsigned short (*As)[40], unsigned short (*Bs)[40]) {
    int tid = threadIdx.x;
    int w = tid >> 6, lane = tid & 63;
    int l16 = lane & 15, lhi = lane >> 4;
    int ar = tid >> 2, ac = tid & 3;
    int gr = idx0[imin(bm + ar, M - 1)];
    const float* aptr = x + (size_t)gr * IN_DIM + ac * 8;

    f32x4 acc[16];
    #pragma unroll
    for (int i = 0; i < 16; i++) acc[i] = (f32x4)0.0f;

    for (int k0 = 0; k0 < IN_DIM; k0 += 32) {
        float4 a0 = *(const float4*)(aptr + k0);
        float4 a1 = *(const float4*)(aptr + k0 + 4);
        unsigned int p0 = (unsigned int)f2bf(a0.x) | ((unsigned int)f2bf(a0.y) << 16);
        unsigned int p1 = (unsigned int)f2bf(a0.z) | ((unsigned int)f2bf(a0.w) << 16);
        unsigned int p2 = (unsigned int)f2bf(a1.x) | ((unsigned int)f2bf(a1.y) << 16);
        unsigned int p3 = (unsigned int)f2bf(a1.z) | ((unsigned int)f2bf(a1.w) << 16);
        *(uint4*)&As[ar][ac * 8] = make_uint4(p0, p1, p2, p3);

        const uint4* bsrc = (const uint4*)(w1s + ((size_t)(k0 >> 5) * 256 + tid) * 32);
        int bswz = (tid >> 3) & 3;
        uint4 b0 = bsrc[0], b1v = bsrc[1], b2 = bsrc[2], b3 = bsrc[3];
        *(uint4*)&Bs[tid][(0 ^ bswz) * 8] = b0;
        *(uint4*)&Bs[tid][(1 ^ bswz) * 8] = b1v;
        *(uint4*)&Bs[tid][(2 ^ bswz) * 8] = b2;
        *(uint4*)&Bs[tid][(3 ^ bswz) * 8] = b3;
        __syncthreads();

        bf16x8 af = *(bf16x8*)&As[w * 16 + l16][lhi * 8];
        #pragma unroll
        for (int f = 0; f < 16; f++) {
            int col = f * 16 + l16;
            bf16x8 bf = *(bf16x8*)&Bs[col][(lhi ^ ((col >> 3) & 3)) * 8];
            acc[f] = __builtin_amdgcn_mfma_f32_16x16x32_bf16(af, bf, acc[f], 0, 0, 0);
        }
        __syncthreads();
    }

    #pragma unroll
    for (int f = 0; f < 16; f++) {
        int col = f * 16 + l16;
        float bb = b1[col];
        #pragma unroll
        for (int reg = 0; reg < 4; reg++) {
            int row = bm + w * 16 + lhi * 4 + reg;
            if (row < M) h0c[(size_t)row * HID + col] = fmaxf(acc[f][reg] + bb, 0.0f);
        }
    }
}

static __device__ void conv_tile(const float* __restrict__ hsrc,
                                 const int* __restrict__ idx, const int* __restrict__ map,
                                 const float* __restrict__ Amsg,
                                 const float* __restrict__ cnt, int cntStride,
                                 const unsigned short* __restrict__ Bt, const float* __restrict__ bias,
                                 float* __restrict__ Cout, int bm, int M,
                                 unsigned short (*As)[40], unsigned short (*Bs)[40]) {
    int tid = threadIdx.x;
    int w = tid >> 6, lane = tid & 63;
    int l16 = lane & 15, lhi = lane >> 4;
    int ar = tid >> 2, ac = tid & 3;
    int row = imin(bm + ar, M - 1);
    int node = idx ? idx[row] : row;
    int grow = map[node]; if (grow < 0) grow = 0;
    const float* rootp = hsrc + (size_t)grow * HID + ac * 8;
    const float* msgp  = Amsg + (size_t)row * MSGW + ac * 8;
    float sc[NREL];
    #pragma unroll
    for (int r = 0; r < NREL; r++)
        sc[r] = 1.0f / fmaxf(cnt[(size_t)r * cntStride + row], 1.0f);

    f32x4 acc[16];
    #pragma unroll
    for (int i = 0; i < 16; i++) acc[i] = (f32x4)0.0f;

    for (int k0 = 0; k0 < KCAT; k0 += 32) {
        float4 a0, a1;
        if (k0 < HID) {
            a0 = *(const float4*)(rootp + k0);
            a1 = *(const float4*)(rootp + k0 + 4);
        } else {
            float s = sc[(k0 - HID) >> 8];
            a0 = *(const float4*)(msgp + (k0 - HID));
            a1 = *(const float4*)(msgp + (k0 - HID) + 4);
            a0.x *= s; a0.y *= s; a0.z *= s; a0.w *= s;
            a1.x *= s; a1.y *= s; a1.z *= s; a1.w *= s;
        }
        unsigned int p0 = (unsigned int)f2bf(a0.x) | ((unsigned int)f2bf(a0.y) << 16);
        unsigned int p1 = (unsigned int)f2bf(a0.z) | ((unsigned int)f2bf(a0.w) << 16);
        unsigned int p2 = (unsigned int)f2bf(a1.x) | ((unsigned int)f2bf(a1.y) << 16);
        unsigned int p3 = (unsigned int)f2bf(a1.z) | ((unsigned int)f2bf(a1.w) << 16);
        *(uint4*)&As[ar][ac * 8] = make_uint4(p0, p1, p2, p3);

        const uint4* bsrc = (const uint4*)(Bt + ((size_t)(k0 >> 5) * 256 + tid) * 32);
        int bswz = (tid >> 3) & 3;
        uint4 b0 = bsrc[0], b1v = bsrc[1], b2 = bsrc[2], b3 = bsrc[3];
        *(uint4*)&Bs[tid][(0 ^ bswz) * 8] = b0;
        *(uint4*)&Bs[tid][(1 ^ bswz) * 8] = b1v;
        *(uint4*)&Bs[tid][(2 ^ bswz) * 8] = b2;
        *(uint4*)&Bs[tid][(3 ^ bswz) * 8] = b3;
        __syncthreads();

        bf16x8 af = *(bf16x8*)&As[w * 16 + l16][lhi * 8];
        #pragma unroll
        for (int f = 0; f < 16; f++) {
            int col = f * 16 + l16;
            bf16x8 bf = *(bf16x8*)&Bs[col][(lhi ^ ((col >> 3) & 3)) * 8];
            acc[f] = __builtin_amdgcn_mfma_f32_16x16x32_bf16(af, bf, acc[f], 0, 0, 0);
        }
        __syncthreads();
    }

    #pragma unroll
    for (int f = 0; f < 16; f++) {
        int col = f * 16 + l16;
        float bb = bias[col];
        #pragma unroll
        for (int reg = 0; reg < 4; reg++) {
            int r = bm + w * 16 + lhi * 4 + reg;
            if (r < M) Cout[(size_t)r * HID + col] = acc[f][reg] + bb;
        }
    }
}

static __device__ void lin2_tile(const float* __restrict__ h2, const float* __restrict__ W2,
                                 const float* __restrict__ b2, const float* __restrict__ Wc,
                                 const float* __restrict__ bc, float* __restrict__ out, int bm,
                                 float (*Asf)[36], float (*Bsf)[132]) {
    int tid = threadIdx.x;
    int tx = tid & 15, ty = tid >> 4;
    int brow = tid >> 4, bch = tid & 15;

    float acc[2][8] = {};

    for (int k0 = 0; k0 < HID; k0 += 16) {
        if (tid < 128) {
            int arow = tid >> 2, ach = tid & 3;
            float4 av = *(const float4*)(h2 + (size_t)(bm + arow) * HID + k0 + ach * 4);
            Asf[ach * 4 + 0][arow] = av.x;
            Asf[ach * 4 + 1][arow] = av.y;
            Asf[ach * 4 + 2][arow] = av.z;
            Asf[ach * 4 + 3][arow] = av.w;
        }
        const float* bp = W2 + (size_t)(k0 + brow) * OUT_DIM;
        *(float4*)&Bsf[brow][bch * 4]      = *(const float4*)(bp + bch * 4);
        *(float4*)&Bsf[brow][64 + bch * 4] = *(const float4*)(bp + 64 + bch * 4);
        __syncthreads();
        #pragma unroll
        for (int k = 0; k < 16; k++) {
            float a0 = Asf[k][ty * 2], a1 = Asf[k][ty * 2 + 1];
            float4 b0 = *(const float4*)&Bsf[k][tx * 8];
            float4 b1 = *(const float4*)&Bsf[k][tx * 8 + 4];
            acc[0][0] += a0 * b0.x; acc[0][1] += a0 * b0.y; acc[0][2] += a0 * b0.z; acc[0][3] += a0 * b0.w;
            acc[0][4] += a0 * b1.x; acc[0][5] += a0 * b1.y; acc[0][6] += a0 * b1.z; acc[0][7] += a0 * b1.w;
            acc[1][0] += a1 * b0.x; acc[1][1] += a1 * b0.y; acc[1][2] += a1 * b0.z; acc[1][3] += a1 * b0.w;
            acc[1][4] += a1 * b1.x; acc[1][5] += a1 * b1.y; acc[1][6] += a1 * b1.z; acc[1][7] += a1 * b1.w;
        }
        __syncthreads();
    }

    float s0[2] = {0.f, 0.f}, s1[2] = {0.f, 0.f};
    #pragma unroll
    for (int j = 0; j < 8; j++) {
        int col = tx * 8 + j;
        float w0 = Wc[col * 2 + 0], w1 = Wc[col * 2 + 1];
        float bb = b2[col];
        #pragma unroll
        for (int i = 0; i < 2; i++) {
            float h = fmaxf(acc[i][j] + bb, 0.0f);
            s0[i] += h * w0;
            s1[i] += h * w1;
        }
    }
    #pragma unroll
    for (int o = 1; o <= 8; o <<= 1) {
        #pragma unroll
        for (int i = 0; i < 2; i++) {
            s0[i] += __shfl_xor(s0[i], o);
            s1[i] += __shfl_xor(s1[i], o);
        }
    }
    if (tx == 0) {
        #pragma unroll
        for (int i = 0; i < 2; i++) {
            int row = bm + ty * 2 + i;
            out[row * 2 + 0] = s0[i] + bc[0];
            out[row * 2 + 1] = s1[i] + bc[1];
        }
    }
}

// ---------------- the megakernel ----------------

__global__ __launch_bounds__(256, 2) void mega(Prm p) {
    __shared__ __align__(16) char sm[(64 * 40 + 256 * 40) * 2];   // 25600 B
    unsigned short (*As)[40] = (unsigned short(*)[40])sm;
    unsigned short (*Bs)[40] = (unsigned short(*)[40])(sm + 64 * 40 * 2);

    const int tid  = threadIdx.x;
    const int gtid = blockIdx.x * 256 + tid;
    const int gstr = gridDim.x * 256;

    // P1: mark sources of edges into S2 (elist2) + bf16 weight prep
    for (int e = gtid; e < N_EDGES; e += gstr) {
        if (p.ei[N_EDGES + e] < BATCH) {
            p.need1[p.ei[e]] = 1;   // benign same-value race
            int q = atomicAdd(p.ectr2, 1);
            if (q < ECAP2) p.elist2[q] = e;
        }
    }
    weight_prep_dev(p, gtid, gstr);
    gbar(p.bar, 0);

    // P2: mark sources of edges into S1 (elist1) + zero Amsg block
    for (int e = gtid; e < N_EDGES; e += gstr) {
        int d = p.ei[N_EDGES + e];
        if (d < BATCH || p.need1[d]) {
            p.need0[p.ei[e]] = 1;
            int q = atomicAdd(p.ectr1, 1);
            if (q < ECAP1) p.elist1[q] = e;
        }
    }
    {
        uint4 z = make_uint4(0u, 0u, 0u, 0u);
        for (int t = gtid; t < p.nz; t += gstr) p.zp[t] = z;
    }
    gbar(p.bar, 1);

    // P3: compact S1 and S0
    for (int i = gtid; i < N_NODES; i += gstr) {
        int f1 = (i < BATCH) | p.need1[i];
        int f0 = f1 | p.need0[i];
        if (f1) {
            int q = atomicAdd(p.n1ctr, 1);
            if (q < CAP1) { p.idx1[q] = i; p.map1[i] = q; } else p.map1[i] = -1;
        } else p.map1[i] = -1;
        if (f0) {
            int q = atomicAdd(p.n0ctr, 1);
            if (q < CAP0) { p.idx0[q] = i; p.map0[i] = q; } else p.map0[i] = -1;
        } else p.map0[i] = -1;
    }
    gbar(p.bar, 2);

    // P4: h0c = relu(x[S0] @ W1 + b1)
    {
        int M = imin(*p.n0ctr, CAP0);
        int nt = (M + 63) >> 6;
        for (int t = blockIdx.x; t < nt; t += gridDim.x)
            gemm1_tile(p.x, p.idx0, p.w1s, p.b1, p.h0c, t * 64, M, As, Bs);
    }
    gbar(p.bar, 3);

    // P5: scatter messages for conv1
    scatter_dev(p.ei, p.et, p.elist1, p.ectr1, ECAP1, p.map0, p.map1, p.h0c,
                p.Amsg1, p.cnt1, CAP1, gtid, gstr);
    gbar(p.bar, 4);

    // P6: conv1
    {
        int M = imin(*p.n1ctr, CAP1);
        int nt = (M + 63) >> 6;
        for (int t = blockIdx.x; t < nt; t += gridDim.x)
            conv_tile(p.h0c, p.idx1, p.map0, p.Amsg1, p.cnt1, CAP1,
                      p.B1s, p.c1bias, p.h1c, t * 64, M, As, Bs);
    }
    gbar(p.bar, 5);

    // P7: scatter messages for conv2
    scatter_dev(p.ei, p.et, p.elist2, p.ectr2, ECAP2, p.map1, nullptr, p.h1c,
                p.Amsg2, p.cnt2, BATCH, gtid, gstr);
    gbar(p.bar, 6);

    // P8: conv2 (rows = node ids 0..1023)
    for (int t = blockIdx.x; t < BATCH / 64; t += gridDim.x)
        conv_tile(p.h1c, nullptr, p.map1, p.Amsg2, p.cnt2, BATCH,
                  p.B2s, p.c2bias, p.h2, t * 64, BATCH, As, Bs);
    gbar(p.bar, 7);

    // P9: logits = relu(h2 @ W2 + b2) @ Wc + bc
    {
        float (*Asf)[36]  = (float(*)[36])sm;
        float (*Bsf)[132] = (float(*)[132])(sm + 16 * 36 * 4);
        for (int t = blockIdx.x; t < BATCH / 32; t += gridDim.x)
            lin2_tile(p.h2, p.W2, p.b2, p.Wc, p.bc, p.out, t * 32, Asf, Bsf);
    }
}

// ---------------- fallback chain (only if occupancy query fails) ----------------

__global__ void fb_zero_prep(Prm p) {
    int t = blockIdx.x * blockDim.x + threadIdx.x;
    if (t < p.nz) { p.zp[t] = make_uint4(0u, 0u, 0u, 0u); return; }
    weight_prep_dev(p, t - p.nz, 1 << 30);
}
__global__ void fb_mark1c(Prm p) {
    int e = blockIdx.x * blockDim.x + threadIdx.x;
    if (e >= N_EDGES) return;
    if (p.ei[N_EDGES + e] < BATCH) {
        p.need1[p.ei[e]] = 1;
        int q = atomicAdd(p.ectr2, 1);
        if (q < ECAP2) p.elist2[q] = e;
    }
}
__global__ void fb_mark0c(Prm p) {
    int e = blockIdx.x * blockDim.x + threadIdx.x;
    if (e >= N_EDGES) return;
    int d = p.ei[N_EDGES + e];
    if (d < BATCH || p.need1[d]) {
        p.need0[p.ei[e]] = 1;
        int q = atomicAdd(p.ectr1, 1);
        if (q < ECAP1) p.elist1[q] = e;
    }
}
__global__ void fb_compact(Prm p) {
    int i = blockIdx.x * blockDim.x + threadIdx.x;
    if (i >= N_NODES) return;
    int f1 = (i < BATCH) | p.need1[i];
    int f0 = f1 | p.need0[i];
    if (f1) {
        int q = atomicAdd(p.n1ctr, 1);
        if (q < CAP1) { p.idx1[q] = i; p.map1[i] = q; } else p.map1[i] = -1;
    } else p.map1[i] = -1;
    if (f0) {
        int q = atomicAdd(p.n0ctr, 1);
        if (q < CAP0) { p.idx0[q] = i; p.map0[i] = q; } else p.map0[i] = -1;
    } else p.map0[i] = -1;
}
__global__ __launch_bounds__(256) void fb_gemm1(Prm p) {
    __shared__ unsigned short As[64][40];
    __shared__ unsigned short Bs[256][40];
    int M = imin(*p.n0ctr, CAP0);
    int bm = blockIdx.x * 64;
    if (bm >= M) return;
    gemm1_tile(p.x, p.idx0, p.w1s, p.b1, p.h0c, bm, M, As, Bs);
}
__global__ void fb_scatter1(Prm p) {
    int g = blockIdx.x * blockDim.x + threadIdx.x;
    scatter_dev(p.ei, p.et, p.elist1, p.ectr1, ECAP1, p.map0, p.map1, p.h0c,
                p.Amsg1, p.cnt1, CAP1, g, 1 << 30);
}
__global__ __launch_bounds__(256) void fb_conv1(Prm p) {
    __shared__ unsigned short As[64][40];
    __shared__ unsigned short Bs[256][40];
    int M = imin(*p.n1ctr, CAP1);
    int bm = blockIdx.x * 64;
    if (bm >= M) return;
    conv_tile(p.h0c, p.idx1, p.map0, p.Amsg1, p.cnt1, CAP1, p.B1s, p.c1bias, p.h1c, bm, M, As, Bs);
}
__global__ void fb_scatter2(Prm p) {
    int g = blockIdx.x * blockDim.x + threadIdx.x;
    scatter_dev(p.ei, p.et, p.elist2, p.ectr2, ECAP2, p.map1, nullptr, p.h1c,
                p.Amsg2, p.cnt2, BATCH, g, 1 << 30);
}
__global__ __launch_bounds__(256) void fb_conv2(Prm p) {
    __shared__ unsigned short As[64][40];
    __shared__ unsigned short Bs[256][40];
    conv_tile(p.h1c, nullptr, p.map1, p.Amsg2, p.cnt2, BATCH, p.B2s, p.c2bias, p.h2,
              blockIdx.x * 64, BATCH, As, Bs);
}
__global__ __launch_bounds__(256) void fb_lin2(Prm p) {
    __shared__ float Asf[16][36];
    __shared__ float Bsf[16][132];
    lin2_tile(p.h2, p.W2, p.b2, p.Wc, p.bc, p.out, blockIdx.x * 32, Asf, Bsf);
}

// ---------------- host ----------------

extern "C" void kernel_launch(void* const* d_in, const int* in_sizes, int n_in,
                              void* d_out, int out_size, void* d_ws, size_t ws_size,
                              hipStream_t stream) {
    Prm p;
    p.x      = (const float*)d_in[0];
    p.ei     = (const int*)d_in[1];
    p.et     = (const int*)d_in[2];
    p.W1     = (const float*)d_in[4];
    p.b1     = (const float*)d_in[5];
    p.c1W    = (const float*)d_in[6];
    p.c1root = (const float*)d_in[7];
    p.c1bias = (const float*)d_in[8];
    p.c2W    = (const float*)d_in[9];
    p.c2root = (const float*)d_in[10];
    p.c2bias = (const float*)d_in[11];
    p.W2     = (const float*)d_in[12];
    p.b2     = (const float*)d_in[13];
    p.Wc     = (const float*)d_in[14];
    p.bc     = (const float*)d_in[15];
    p.out    = (float*)d_out;

    char* ws = (char*)d_ws;
    size_t off = 0;
    auto alloc = [&](size_t bytes) -> char* {
        char* q = ws + off;
        off = (off + bytes + 255) & ~(size_t)255;
        return q;
    };

    // --- memset region: barrier slots + ctrs + cnt1 + cnt2 + need1 + need0 ---
    p.bar = (int*)alloc((size_t)NBAR * BLINES * 64);      // 36 KB
    size_t zb_ctr  = 16;
    size_t zb_cnt1 = (size_t)NREL * CAP1 * 4;
    size_t zb_cnt2 = (size_t)NREL * BATCH * 4;
    size_t zb_need = (size_t)N_NODES * 4;
    char* zsmall = alloc(zb_ctr + zb_cnt1 + zb_cnt2 + 2 * zb_need);
    p.n1ctr = (int*)zsmall;
    p.n0ctr = p.n1ctr + 1;
    p.ectr1 = p.n1ctr + 2;
    p.ectr2 = p.n1ctr + 3;
    p.cnt1  = (float*)(zsmall + zb_ctr);
    p.cnt2  = (float*)(zsmall + zb_ctr + zb_cnt1);
    p.need1 = (int*)(zsmall + zb_ctr + zb_cnt1 + zb_cnt2);
    p.need0 = (int*)((char*)p.need1 + zb_need);
    size_t msbytes = (size_t)(((char*)p.need0 + zb_need) - (char*)p.bar);

    // --- Amsg region (zeroed in-kernel, phase P2) ---
    size_t zb_amsg1 = (size_t)CAP1 * MSGW * 4;
    size_t zb_amsg2 = (size_t)BATCH * MSGW * 4;
    char* amsg = alloc(zb_amsg1 + zb_amsg2);
    p.zp    = (uint4*)amsg;
    p.nz    = (int)((zb_amsg1 + zb_amsg2) / 16);
    p.Amsg1 = (float*)amsg;
    p.Amsg2 = (float*)(amsg + zb_amsg1);

    p.map1   = (int*)alloc(N_NODES * 4);
    p.map0   = (int*)alloc(N_NODES * 4);
    p.idx1   = (int*)alloc(CAP1 * 4);
    p.idx0   = (int*)alloc(CAP0 * 4);
    p.elist1 = (int*)alloc(ECAP1 * 4);
    p.elist2 = (int*)alloc(ECAP2 * 4);
    p.h0c    = (float*)alloc((size_t)CAP0 * HID * 4);
    p.h1c    = (float*)alloc((size_t)CAP1 * HID * 4);
    p.h2     = (float*)alloc((size_t)BATCH * HID * 4);
    p.w1s    = (unsigned short*)alloc((size_t)IN_DIM * HID * 2);
    p.B1s    = (unsigned short*)alloc((size_t)KCAT * HID * 2);
    p.B2s    = (unsigned short*)alloc((size_t)KCAT * HID * 2);
    (void)ws_size; (void)in_sizes; (void)n_in; (void)out_size;

    // node 1: zero barriers + ctrs + cnts + flags (~1 MB)
    hipMemsetAsync(p.bar, 0, msbytes, stream);

    // co-residency check (pure query; capture-safe, deterministic)
    int occ = 0;
    hipError_t qe = hipOccupancyMaxActiveBlocksPerMultiprocessor(&occ, mega, 256, 0);

    if (qe == hipSuccess && occ >= 1) {
        int nblk = (occ >= 2) ? 512 : 256;   // multiple of 64; all co-resident
        // node 2: the whole pipeline
        mega<<<dim3(nblk), dim3(256), 0, stream>>>(p);
    } else {
        // fallback: 10-kernel chain (known-good)
        const int NB = 256;
        int prep_threads = (IN_DIM * HID) / 8 + 2 * (KCAT * HID) / 8;
        int zp_total = p.nz + prep_threads;
        fb_zero_prep<<<dim3((zp_total + NB - 1) / NB), NB, 0, stream>>>(p);
        fb_mark1c<<<dim3((N_EDGES + NB - 1) / NB), NB, 0, stream>>>(p);
        fb_mark0c<<<dim3((N_EDGES + NB - 1) / NB), NB, 0, stream>>>(p);
        fb_compact<<<dim3((N_NODES + NB - 1) / NB), NB, 0, stream>>>(p);
        fb_gemm1<<<dim3(CAP0 / 64), NB, 0, stream>>>(p);
        fb_scatter1<<<dim3(ECAP1 * 64 / NB), NB, 0, stream>>>(p);
        fb_conv1<<<dim3(CAP1 / 64), NB, 0, stream>>>(p);
        fb_scatter2<<<dim3(ECAP2 * 64 / NB), NB, 0, stream>>>(p);
        fb_conv2<<<dim3(BATCH / 64), NB, 0, stream>>>(p);
        fb_lin2<<<dim3(BATCH / 32), NB, 0, stream>>>(p);
    }
}

// Round 8
// 467.189 us; speedup vs baseline: 1.0094x; 1.0015x over previous
//
#include <hip/hip_runtime.h>

// RGCN pruned to the 2-hop cone of the first 1024 nodes.
// R8: megakernel with XCD-aware barriers. R6 (1-line) and R7 (64-line)
// barriers performed identically -> arrival contention is not the cost; the
// per-block __threadfence (L2 writeback x512) + per-poll acquire (inv) is the
// suspect. New barrier: relaxed arrive per-XCD; LAST block on each XCD does
// the ONE release fence (8 wbl2/barrier instead of 512); relaxed spin; one
// acquire fence per block on exit. XCD id via s_getreg(HW_REG_XCC_ID).

#define N_NODES 100000
#define N_EDGES 400000
#define IN_DIM  768
#define HID     256
#define OUT_DIM 128
#define NREL    3
#define BATCH   1024
#define KCAT    1024   // HID*(NREL+1)
#define MSGW    768    // NREL*HID
#define CAP0    32768  // |S0| ~23K
#define CAP1    8192   // |S1| ~5K
#define ECAP1   32768  // edges into S1 ~20K
#define ECAP2   8192   // edges into S2 ~4.1K

// barrier region layout (ints; one slot line = 16 ints = 64B)
#define FULL_OFF  0            // 64 lines: full barrier (slot 0 / registration)
#define XCNT_OFF  1024         // 8 lines: blocks per XCD
#define ARR_OFF   1152         // 7 slots x 8 xcd lines
#define DONE_OFF  2048         // 7 lines: flushDone per fast slot
#define BAR_INTS  2176

typedef __attribute__((ext_vector_type(8))) short bf16x8;
typedef __attribute__((ext_vector_type(4))) float f32x4;

static __device__ __forceinline__ int imin(int a, int b) { return a < b ? a : b; }

static __device__ __forceinline__ unsigned short f2bf(float f) {
    union { float f; unsigned int u; } v; v.f = f;
    unsigned int r = v.u + 0x7FFFu + ((v.u >> 16) & 1u);   // RNE
    return (unsigned short)(r >> 16);
}

struct Prm {
    const float* x; const int* ei; const int* et;
    const float *W1, *b1, *c1W, *c1root, *c1bias, *c2W, *c2root, *c2bias, *W2, *b2, *Wc, *bc;
    float* out;
    uint4* zp; int nz;            // Amsg region (zeroed in-kernel, P2)
    int* bar;                     // BAR_INTS ints, pre-zeroed by memset
    int *need1, *need0, *map1, *map0, *idx1, *idx0, *elist1, *elist2;
    int *n1ctr, *n0ctr, *ectr1, *ectr2;
    float *cnt1, *cnt2, *Amsg1, *Amsg2, *h0c, *h1c, *h2;
    unsigned short *w1s, *B1s, *B2s;
};

// ---- full barrier (slot 0 only; 64-line arrive, known-good from R7) ----
static __device__ __forceinline__ void gbar_full(int* bar) {
    __syncthreads();
    int* base = bar + FULL_OFF;
    if (threadIdx.x == 0) {
        __threadfence();
        atomicAdd(base + (blockIdx.x & 63) * 16, 1);
    }
    if (threadIdx.x < 64) {
        int target = (int)(gridDim.x >> 6);
        int* line = base + threadIdx.x * 16;
        long spins = 0;
        while (__hip_atomic_load(line, __ATOMIC_ACQUIRE, __HIP_MEMORY_SCOPE_AGENT) < target) {
            __builtin_amdgcn_s_sleep(4);
            if (++spins > (1L << 22)) break;
        }
        __threadfence();
    }
    __syncthreads();
}

// ---- fast XCD barrier (slots 0..6): 8 release-flushes total, relaxed spin ----
static __device__ __forceinline__ void gbar_fast(int* bar, int slot, int xcd,
                                                 int cntMy, int nAct) {
    __syncthreads();   // drains block's vmem (compiler emits waitcnt before barrier)
    if (threadIdx.x == 0) {
        int* done = bar + DONE_OFF + slot * 16;
        if (nAct >= 2) {
            int* arr = bar + ARR_OFF + (slot * 8 + xcd) * 16;
            int a = atomicAdd(arr, 1) + 1;            // relaxed RMW at coherence point
            if (a == cntMy) {
                // last arriver on this XCD: all this-XCD blocks' stores are in
                // this L2 -> ONE release flush covers them all.
                __builtin_amdgcn_fence(__ATOMIC_RELEASE, "agent");
                atomicAdd(done, 1);
            }
            long spins = 0;
            while (__hip_atomic_load(done, __ATOMIC_RELAXED, __HIP_MEMORY_SCOPE_AGENT) < nAct) {
                __builtin_amdgcn_s_sleep(4);
                if (++spins > (1L << 22)) break;
            }
            __builtin_amdgcn_fence(__ATOMIC_ACQUIRE, "agent");   // one inv per block
        } else {
            // degenerate XCC_ID readings -> R7-style safe path
            __threadfence();
            atomicAdd(done, 1);
            long spins = 0;
            while (__hip_atomic_load(done, __ATOMIC_ACQUIRE, __HIP_MEMORY_SCOPE_AGENT) < (int)gridDim.x) {
                __builtin_amdgcn_s_sleep(4);
                if (++spins > (1L << 22)) break;
            }
            __threadfence();
        }
    }
    __syncthreads();
}

// ---------------- device phase helpers (verified R2-R7) ----------------

static __device__ void weight_prep_dev(const Prm& p, int gtid, int gstr) {
    const int P1n = (IN_DIM * HID) / 8, P2n = (KCAT * HID) / 8;
    for (int u = gtid; u < P1n + 2 * P2n; u += gstr) {
        unsigned int pk[4];
        if (u < P1n) {
            int base = u * 8;
            int j0 = base & 31, c = (base >> 5) & 255, s = base >> 13;
            #pragma unroll
            for (int q = 0; q < 4; q++) {
                unsigned short lo = f2bf(p.W1[((s * 32 + j0 + 2 * q) << 8) + c]);
                unsigned short hi = f2bf(p.W1[((s * 32 + j0 + 2 * q + 1) << 8) + c]);
                pk[q] = (unsigned int)lo | ((unsigned int)hi << 16);
            }
            *(uint4*)&p.w1s[base] = make_uint4(pk[0], pk[1], pk[2], pk[3]);
        } else {
            int which2 = (u - P1n) >= P2n;
            const float* root = which2 ? p.c2root : p.c1root;
            const float* Wr   = which2 ? p.c2W : p.c1W;
            unsigned short* dst = which2 ? p.B2s : p.B1s;
            int base = ((u - P1n) - (which2 ? P2n : 0)) * 8;
            int j0 = base & 31, c = (base >> 5) & 255, s = base >> 13;
            int k0 = s * 32 + j0;
            #pragma unroll
            for (int q = 0; q < 4; q++) {
                int ka = k0 + 2 * q, kb = ka + 1;
                float va = (ka < HID) ? root[(ka << 8) + c] : Wr[((ka - HID) << 8) + c];
                float vb = (kb < HID) ? root[(kb << 8) + c] : Wr[((kb - HID) << 8) + c];
                pk[q] = (unsigned int)f2bf(va) | ((unsigned int)f2bf(vb) << 16);
            }
            *(uint4*)&dst[base] = make_uint4(pk[0], pk[1], pk[2], pk[3]);
        }
    }
}

static __device__ void scatter_dev(const int* __restrict__ ei, const int* __restrict__ et,
                                   const int* __restrict__ elist, const int* __restrict__ ectr, int ecap,
                                   const int* __restrict__ mapSrc, const int* __restrict__ mapDst,
                                   const float* __restrict__ hsrc,
                                   float* __restrict__ Amsg, float* __restrict__ cnt,
                                   int cntStride, int gtid, int gstr) {
    int n = imin(*ectr, ecap);
    int tot = n * 64;
    for (int g = gtid; g < tot; g += gstr) {
        int ii = g >> 6, lane = g & 63;
        int e = elist[ii];
        int d = ei[N_EDGES + e];
        int row = mapDst ? mapDst[d] : d;
        if (row < 0) continue;
        int s = mapSrc[ei[e]];
        if (s < 0) continue;
        int r = et[e];
        float4 v = *(const float4*)(hsrc + (size_t)s * HID + lane * 4);
        float* dp = Amsg + (size_t)row * MSGW + (size_t)r * HID + lane * 4;
        atomicAdd(dp + 0, v.x);
        atomicAdd(dp + 1, v.y);
        atomicAdd(dp + 2, v.z);
        atomicAdd(dp + 3, v.w);
        if (lane == 0) atomicAdd(cnt + (size_t)r * cntStride + row, 1.0f);
    }
}

static __device__ void gemm1_tile(const float* __restrict__ x, const int* __restrict__ idx0,
                                  const unsigned short* __restrict__ w1s, const float* __restrict__ b1,
                                  float* __restrict__ h0c, int bm, int M,
                                  unsigned short (*As)[40], unsigned short (*Bs)[40]) {
    int tid = threadIdx.x;
    int w = tid >> 6, lane = tid & 63;
    int l16 = lane & 15, lhi = lane >> 4;
    int ar = tid >> 2, ac = tid & 3;
    int gr = idx0[imin(bm + ar, M - 1)];
    const float* aptr = x + (size_t)gr * IN_DIM + ac * 8;

    f32x4 acc[16];
    #pragma unroll
    for (int i = 0; i < 16; i++) acc[i] = (f32x4)0.0f;

    for (int k0 = 0; k0 < IN_DIM; k0 += 32) {
        float4 a0 = *(const float4*)(aptr + k0);
        float4 a1 = *(const float4*)(aptr + k0 + 4);
        unsigned int p0 = (unsigned int)f2bf(a0.x) | ((unsigned int)f2bf(a0.y) << 16);
        unsigned int p1 = (unsigned int)f2bf(a0.z) | ((unsigned int)f2bf(a0.w) << 16);
        unsigned int p2 = (unsigned int)f2bf(a1.x) | ((unsigned int)f2bf(a1.y) << 16);
        unsigned int p3 = (unsigned int)f2bf(a1.z) | ((unsigned int)f2bf(a1.w) << 16);
        *(uint4*)&As[ar][ac * 8] = make_uint4(p0, p1, p2, p3);

        const uint4* bsrc = (const uint4*)(w1s + ((size_t)(k0 >> 5) * 256 + tid) * 32);
        int bswz = (tid >> 3) & 3;
        uint4 b0 = bsrc[0], b1v = bsrc[1], b2 = bsrc[2], b3 = bsrc[3];
        *(uint4*)&Bs[tid][(0 ^ bswz) * 8] = b0;
        *(uint4*)&Bs[tid][(1 ^ bswz) * 8] = b1v;
        *(uint4*)&Bs[tid][(2 ^ bswz) * 8] = b2;
        *(uint4*)&Bs[tid][(3 ^ bswz) * 8] = b3;
        __syncthreads();

        bf16x8 af = *(bf16x8*)&As[w * 16 + l16][lhi * 8];
        #pragma unroll
        for (int f = 0; f < 16; f++) {
            int col = f * 16 + l16;
            bf16x8 bf = *(bf16x8*)&Bs[col][(lhi ^ ((col >> 3) & 3)) * 8];
            acc[f] = __builtin_amdgcn_mfma_f32_16x16x32_bf16(af, bf, acc[f], 0, 0, 0);
        }
        __syncthreads();
    }

    #pragma unroll
    for (int f = 0; f < 16; f++) {
        int col = f * 16 + l16;
        float bb = b1[col];
        #pragma unroll
        for (int reg = 0; reg < 4; reg++) {
            int row = bm + w * 16 + lhi * 4 + reg;
            if (row < M) h0c[(size_t)row * HID + col] = fmaxf(acc[f][reg] + bb, 0.0f);
        }
    }
}

static __device__ void conv_tile(const float* __restrict__ hsrc,
                                 const int* __restrict__ idx, const int* __restrict__ map,
                                 const float* __restrict__ Amsg,
                                 const float* __restrict__ cnt, int cntStride,
                                 const unsigned short* __restrict__ Bt, const float* __restrict__ bias,
                                 float* __restrict__ Cout, int bm, int M,
                                 unsigned short (*As)[40], unsigned short (*Bs)[40]) {
    int tid = threadIdx.x;
    int w = tid >> 6, lane = tid & 63;
    int l16 = lane & 15, lhi = lane >> 4;
    int ar = tid >> 2, ac = tid & 3;
    int row = imin(bm + ar, M - 1);
    int node = idx ? idx[row] : row;
    int grow = map[node]; if (grow < 0) grow = 0;
    const float* rootp = hsrc + (size_t)grow * HID + ac * 8;
    const float* msgp  = Amsg + (size_t)row * MSGW + ac * 8;
    float sc[NREL];
    #pragma unroll
    for (int r = 0; r < NREL; r++)
        sc[r] = 1.0f / fmaxf(cnt[(size_t)r * cntStride + row], 1.0f);

    f32x4 acc[16];
    #pragma unroll
    for (int i = 0; i < 16; i++) acc[i] = (f32x4)0.0f;

    for (int k0 = 0; k0 < KCAT; k0 += 32) {
        float4 a0, a1;
        if (k0 < HID) {
            a0 = *(const float4*)(rootp + k0);
            a1 = *(const float4*)(rootp + k0 + 4);
        } else {
            float s = sc[(k0 - HID) >> 8];
            a0 = *(const float4*)(msgp + (k0 - HID));
            a1 = *(const float4*)(msgp + (k0 - HID) + 4);
            a0.x *= s; a0.y *= s; a0.z *= s; a0.w *= s;
            a1.x *= s; a1.y *= s; a1.z *= s; a1.w *= s;
        }
        unsigned int p0 = (unsigned int)f2bf(a0.x) | ((unsigned int)f2bf(a0.y) << 16);
        unsigned int p1 = (unsigned int)f2bf(a0.z) | ((unsigned int)f2bf(a0.w) << 16);
        unsigned int p2 = (unsigned int)f2bf(a1.x) | ((unsigned int)f2bf(a1.y) << 16);
        unsigned int p3 = (unsigned int)f2bf(a1.z) | ((unsigned int)f2bf(a1.w) << 16);
        *(uint4*)&As[ar][ac * 8] = make_uint4(p0, p1, p2, p3);

        const uint4* bsrc = (const uint4*)(Bt + ((size_t)(k0 >> 5) * 256 + tid) * 32);
        int bswz = (tid >> 3) & 3;
        uint4 b0 = bsrc[0], b1v = bsrc[1], b2 = bsrc[2], b3 = bsrc[3];
        *(uint4*)&Bs[tid][(0 ^ bswz) * 8] = b0;
        *(uint4*)&Bs[tid][(1 ^ bswz) * 8] = b1v;
        *(uint4*)&Bs[tid][(2 ^ bswz) * 8] = b2;
        *(uint4*)&Bs[tid][(3 ^ bswz) * 8] = b3;
        __syncthreads();

        bf16x8 af = *(bf16x8*)&As[w * 16 + l16][lhi * 8];
        #pragma unroll
        for (int f = 0; f < 16; f++) {
            int col = f * 16 + l16;
            bf16x8 bf = *(bf16x8*)&Bs[col][(lhi ^ ((col >> 3) & 3)) * 8];
            acc[f] = __builtin_amdgcn_mfma_f32_16x16x32_bf16(af, bf, acc[f], 0, 0, 0);
        }
        __syncthreads();
    }

    #pragma unroll
    for (int f = 0; f < 16; f++) {
        int col = f * 16 + l16;
        float bb = bias[col];
        #pragma unroll
        for (int reg = 0; reg < 4; reg++) {
            int r = bm + w * 16 + lhi * 4 + reg;
            if (r < M) Cout[(size_t)r * HID + col] = acc[f][reg] + bb;
        }
    }
}

static __device__ void lin2_tile(const float* __restrict__ h2, const float* __restrict__ W2,
                                 const float* __restrict__ b2, const float* __restrict__ Wc,
                                 const float* __restrict__ bc, float* __restrict__ out, int bm,
                                 float (*Asf)[36], float (*Bsf)[132]) {
    int tid = threadIdx.x;
    int tx = tid & 15, ty = tid >> 4;
    int brow = tid >> 4, bch = tid & 15;

    float acc[2][8] = {};

    for (int k0 = 0; k0 < HID; k0 += 16) {
        if (tid < 128) {
            int arow = tid >> 2, ach = tid & 3;
            float4 av = *(const float4*)(h2 + (size_t)(bm + arow) * HID + k0 + ach * 4);
            Asf[ach * 4 + 0][arow] = av.x;
            Asf[ach * 4 + 1][arow] = av.y;
            Asf[ach * 4 + 2][arow] = av.z;
            Asf[ach * 4 + 3][arow] = av.w;
        }
        const float* bp = W2 + (size_t)(k0 + brow) * OUT_DIM;
        *(float4*)&Bsf[brow][bch * 4]      = *(const float4*)(bp + bch * 4);
        *(float4*)&Bsf[brow][64 + bch * 4] = *(const float4*)(bp + 64 + bch * 4);
        __syncthreads();
        #pragma unroll
        for (int k = 0; k < 16; k++) {
            float a0 = Asf[k][ty * 2], a1 = Asf[k][ty * 2 + 1];
            float4 b0 = *(const float4*)&Bsf[k][tx * 8];
            float4 b1 = *(const float4*)&Bsf[k][tx * 8 + 4];
            acc[0][0] += a0 * b0.x; acc[0][1] += a0 * b0.y; acc[0][2] += a0 * b0.z; acc[0][3] += a0 * b0.w;
            acc[0][4] += a0 * b1.x; acc[0][5] += a0 * b1.y; acc[0][6] += a0 * b1.z; acc[0][7] += a0 * b1.w;
            acc[1][0] += a1 * b0.x; acc[1][1] += a1 * b0.y; acc[1][2] += a1 * b0.z; acc[1][3] += a1 * b0.w;
            acc[1][4] += a1 * b1.x; acc[1][5] += a1 * b1.y; acc[1][6] += a1 * b1.z; acc[1][7] += a1 * b1.w;
        }
        __syncthreads();
    }

    float s0[2] = {0.f, 0.f}, s1[2] = {0.f, 0.f};
    #pragma unroll
    for (int j = 0; j < 8; j++) {
        int col = tx * 8 + j;
        float w0 = Wc[col * 2 + 0], w1 = Wc[col * 2 + 1];
        float bb = b2[col];
        #pragma unroll
        for (int i = 0; i < 2; i++) {
            float h = fmaxf(acc[i][j] + bb, 0.0f);
            s0[i] += h * w0;
            s1[i] += h * w1;
        }
    }
    #pragma unroll
    for (int o = 1; o <= 8; o <<= 1) {
        #pragma unroll
        for (int i = 0; i < 2; i++) {
            s0[i] += __shfl_xor(s0[i], o);
            s1[i] += __shfl_xor(s1[i], o);
        }
    }
    if (tx == 0) {
        #pragma unroll
        for (int i = 0; i < 2; i++) {
            int row = bm + ty * 2 + i;
            out[row * 2 + 0] = s0[i] + bc[0];
            out[row * 2 + 1] = s1[i] + bc[1];
        }
    }
}

// ---------------- the megakernel ----------------

__global__ __launch_bounds__(256, 2) void mega(Prm p) {
    __shared__ __align__(16) char sm[(64 * 40 + 256 * 40) * 2];   // 25600 B
    unsigned short (*As)[40] = (unsigned short(*)[40])sm;
    unsigned short (*Bs)[40] = (unsigned short(*)[40])(sm + 64 * 40 * 2);
    __shared__ int s_xcd, s_cnt, s_nact;

    const int tid  = threadIdx.x;
    const int gtid = blockIdx.x * 256 + tid;
    const int gstr = gridDim.x * 256;

    // registration: record this block's physical XCD
    if (tid == 0) {
        unsigned x = __builtin_amdgcn_s_getreg((31 << 11) | 20) & 7u;  // HW_REG_XCC_ID
        s_xcd = (int)x;
        atomicAdd(p.bar + XCNT_OFF + (int)x * 16, 1);
    }
    __syncthreads();
    const int xcd = s_xcd;

    // P1: mark sources of edges into S2 (elist2) + bf16 weight prep
    for (int e = gtid; e < N_EDGES; e += gstr) {
        if (p.ei[N_EDGES + e] < BATCH) {
            p.need1[p.ei[e]] = 1;   // benign same-value race
            int q = atomicAdd(p.ectr2, 1);
            if (q < ECAP2) p.elist2[q] = e;
        }
    }
    weight_prep_dev(p, gtid, gstr);
    gbar_full(p.bar);                           // barrier 1 (registration resolves here)

    if (tid == 0) {
        int na = 0, cm = 0;
        #pragma unroll
        for (int k = 0; k < 8; k++) {
            int c = p.bar[XCNT_OFF + k * 16];
            na += (c > 0);
            if (k == xcd) cm = c;
        }
        s_cnt = cm; s_nact = na;
    }
    __syncthreads();
    const int cntMy = s_cnt, nAct = s_nact;

    // P2: mark sources of edges into S1 (elist1) + zero Amsg block
    for (int e = gtid; e < N_EDGES; e += gstr) {
        int d = p.ei[N_EDGES + e];
        if (d < BATCH || p.need1[d]) {
            p.need0[p.ei[e]] = 1;
            int q = atomicAdd(p.ectr1, 1);
            if (q < ECAP1) p.elist1[q] = e;
        }
    }
    {
        uint4 z = make_uint4(0u, 0u, 0u, 0u);
        for (int t = gtid; t < p.nz; t += gstr) p.zp[t] = z;
    }
    gbar_fast(p.bar, 0, xcd, cntMy, nAct);      // barrier 2

    // P3: compact S1 and S0
    for (int i = gtid; i < N_NODES; i += gstr) {
        int f1 = (i < BATCH) | p.need1[i];
        int f0 = f1 | p.need0[i];
        if (f1) {
            int q = atomicAdd(p.n1ctr, 1);
            if (q < CAP1) { p.idx1[q] = i; p.map1[i] = q; } else p.map1[i] = -1;
        } else p.map1[i] = -1;
        if (f0) {
            int q = atomicAdd(p.n0ctr, 1);
            if (q < CAP0) { p.idx0[q] = i; p.map0[i] = q; } else p.map0[i] = -1;
        } else p.map0[i] = -1;
    }
    gbar_fast(p.bar, 1, xcd, cntMy, nAct);      // barrier 3

    // P4: h0c = relu(x[S0] @ W1 + b1)
    {
        int M = imin(*p.n0ctr, CAP0);
        int nt = (M + 63) >> 6;
        for (int t = blockIdx.x; t < nt; t += gridDim.x)
            gemm1_tile(p.x, p.idx0, p.w1s, p.b1, p.h0c, t * 64, M, As, Bs);
    }
    gbar_fast(p.bar, 2, xcd, cntMy, nAct);      // barrier 4

    // P5: scatter messages for conv1
    scatter_dev(p.ei, p.et, p.elist1, p.ectr1, ECAP1, p.map0, p.map1, p.h0c,
                p.Amsg1, p.cnt1, CAP1, gtid, gstr);
    gbar_fast(p.bar, 3, xcd, cntMy, nAct);      // barrier 5

    // P6: conv1
    {
        int M = imin(*p.n1ctr, CAP1);
        int nt = (M + 63) >> 6;
        for (int t = blockIdx.x; t < nt; t += gridDim.x)
            conv_tile(p.h0c, p.idx1, p.map0, p.Amsg1, p.cnt1, CAP1,
                      p.B1s, p.c1bias, p.h1c, t * 64, M, As, Bs);
    }
    gbar_fast(p.bar, 4, xcd, cntMy, nAct);      // barrier 6

    // P7: scatter messages for conv2
    scatter_dev(p.ei, p.et, p.elist2, p.ectr2, ECAP2, p.map1, nullptr, p.h1c,
                p.Amsg2, p.cnt2, BATCH, gtid, gstr);
    gbar_fast(p.bar, 5, xcd, cntMy, nAct);      // barrier 7

    // P8: conv2 (rows = node ids 0..1023)
    for (int t = blockIdx.x; t < BATCH / 64; t += gridDim.x)
        conv_tile(p.h1c, nullptr, p.map1, p.Amsg2, p.cnt2, BATCH,
                  p.B2s, p.c2bias, p.h2, t * 64, BATCH, As, Bs);
    gbar_fast(p.bar, 6, xcd, cntMy, nAct);      // barrier 8

    // P9: logits = relu(h2 @ W2 + b2) @ Wc + bc
    {
        float (*Asf)[36]  = (float(*)[36])sm;
        float (*Bsf)[132] = (float(*)[132])(sm + 16 * 36 * 4);
        for (int t = blockIdx.x; t < BATCH / 32; t += gridDim.x)
            lin2_tile(p.h2, p.W2, p.b2, p.Wc, p.bc, p.out, t * 32, Asf, Bsf);
    }
}

// ---------------- fallback chain (only if occupancy query fails) ----------------

__global__ void fb_zero_prep(Prm p) {
    int t = blockIdx.x * blockDim.x + threadIdx.x;
    if (t < p.nz) { p.zp[t] = make_uint4(0u, 0u, 0u, 0u); return; }
    weight_prep_dev(p, t - p.nz, 1 << 30);
}
__global__ void fb_mark1c(Prm p) {
    int e = blockIdx.x * blockDim.x + threadIdx.x;
    if (e >= N_EDGES) return;
    if (p.ei[N_EDGES + e] < BATCH) {
        p.need1[p.ei[e]] = 1;
        int q = atomicAdd(p.ectr2, 1);
        if (q < ECAP2) p.elist2[q] = e;
    }
}
__global__ void fb_mark0c(Prm p) {
    int e = blockIdx.x * blockDim.x + threadIdx.x;
    if (e >= N_EDGES) return;
    int d = p.ei[N_EDGES + e];
    if (d < BATCH || p.need1[d]) {
        p.need0[p.ei[e]] = 1;
        int q = atomicAdd(p.ectr1, 1);
        if (q < ECAP1) p.elist1[q] = e;
    }
}
__global__ void fb_compact(Prm p) {
    int i = blockIdx.x * blockDim.x + threadIdx.x;
    if (i >= N_NODES) return;
    int f1 = (i < BATCH) | p.need1[i];
    int f0 = f1 | p.need0[i];
    if (f1) {
        int q = atomicAdd(p.n1ctr, 1);
        if (q < CAP1) { p.idx1[q] = i; p.map1[i] = q; } else p.map1[i] = -1;
    } else p.map1[i] = -1;
    if (f0) {
        int q = atomicAdd(p.n0ctr, 1);
        if (q < CAP0) { p.idx0[q] = i; p.map0[i] = q; } else p.map0[i] = -1;
    } else p.map0[i] = -1;
}
__global__ __launch_bounds__(256) void fb_gemm1(Prm p) {
    __shared__ unsigned short As[64][40];
    __shared__ unsigned short Bs[256][40];
    int M = imin(*p.n0ctr, CAP0);
    int bm = blockIdx.x * 64;
    if (bm >= M) return;
    gemm1_tile(p.x, p.idx0, p.w1s, p.b1, p.h0c, bm, M, As, Bs);
}
__global__ void fb_scatter1(Prm p) {
    int g = blockIdx.x * blockDim.x + threadIdx.x;
    scatter_dev(p.ei, p.et, p.elist1, p.ectr1, ECAP1, p.map0, p.map1, p.h0c,
                p.Amsg1, p.cnt1, CAP1, g, 1 << 30);
}
__global__ __launch_bounds__(256) void fb_conv1(Prm p) {
    __shared__ unsigned short As[64][40];
    __shared__ unsigned short Bs[256][40];
    int M = imin(*p.n1ctr, CAP1);
    int bm = blockIdx.x * 64;
    if (bm >= M) return;
    conv_tile(p.h0c, p.idx1, p.map0, p.Amsg1, p.cnt1, CAP1, p.B1s, p.c1bias, p.h1c, bm, M, As, Bs);
}
__global__ void fb_scatter2(Prm p) {
    int g = blockIdx.x * blockDim.x + threadIdx.x;
    scatter_dev(p.ei, p.et, p.elist2, p.ectr2, ECAP2, p.map1, nullptr, p.h1c,
                p.Amsg2, p.cnt2, BATCH, g, 1 << 30);
}
__global__ __launch_bounds__(256) void fb_conv2(Prm p) {
    __shared__ unsigned short As[64][40];
    __shared__ unsigned short Bs[256][40];
    conv_tile(p.h1c, nullptr, p.map1, p.Amsg2, p.cnt2, BATCH, p.B2s, p.c2bias, p.h2,
              blockIdx.x * 64, BATCH, As, Bs);
}
__global__ __launch_bounds__(256) void fb_lin2(Prm p) {
    __shared__ float Asf[16][36];
    __shared__ float Bsf[16][132];
    lin2_tile(p.h2, p.W2, p.b2, p.Wc, p.bc, p.out, blockIdx.x * 32, Asf, Bsf);
}

// ---------------- host ----------------

extern "C" void kernel_launch(void* const* d_in, const int* in_sizes, int n_in,
                              void* d_out, int out_size, void* d_ws, size_t ws_size,
                              hipStream_t stream) {
    Prm p;
    p.x      = (const float*)d_in[0];
    p.ei     = (const int*)d_in[1];
    p.et     = (const int*)d_in[2];
    p.W1     = (const float*)d_in[4];
    p.b1     = (const float*)d_in[5];
    p.c1W    = (const float*)d_in[6];
    p.c1root = (const float*)d_in[7];
    p.c1bias = (const float*)d_in[8];
    p.c2W    = (const float*)d_in[9];
    p.c2root = (const float*)d_in[10];
    p.c2bias = (const float*)d_in[11];
    p.W2     = (const float*)d_in[12];
    p.b2     = (const float*)d_in[13];
    p.Wc     = (const float*)d_in[14];
    p.bc     = (const float*)d_in[15];
    p.out    = (float*)d_out;

    char* ws = (char*)d_ws;
    size_t off = 0;
    auto alloc = [&](size_t bytes) -> char* {
        char* q = ws + off;
        off = (off + bytes + 255) & ~(size_t)255;
        return q;
    };

    // --- memset region: barrier ints + ctrs + cnt1 + cnt2 + need1 + need0 ---
    p.bar = (int*)alloc((size_t)BAR_INTS * 4);
    size_t zb_ctr  = 16;
    size_t zb_cnt1 = (size_t)NREL * CAP1 * 4;
    size_t zb_cnt2 = (size_t)NREL * BATCH * 4;
    size_t zb_need = (size_t)N_NODES * 4;
    char* zsmall = alloc(zb_ctr + zb_cnt1 + zb_cnt2 + 2 * zb_need);
    p.n1ctr = (int*)zsmall;
    p.n0ctr = p.n1ctr + 1;
    p.ectr1 = p.n1ctr + 2;
    p.ectr2 = p.n1ctr + 3;
    p.cnt1  = (float*)(zsmall + zb_ctr);
    p.cnt2  = (float*)(zsmall + zb_ctr + zb_cnt1);
    p.need1 = (int*)(zsmall + zb_ctr + zb_cnt1 + zb_cnt2);
    p.need0 = (int*)((char*)p.need1 + zb_need);
    size_t msbytes = (size_t)(((char*)p.need0 + zb_need) - (char*)p.bar);

    // --- Amsg region (zeroed in-kernel, phase P2) ---
    size_t zb_amsg1 = (size_t)CAP1 * MSGW * 4;
    size_t zb_amsg2 = (size_t)BATCH * MSGW * 4;
    char* amsg = alloc(zb_amsg1 + zb_amsg2);
    p.zp    = (uint4*)amsg;
    p.nz    = (int)((zb_amsg1 + zb_amsg2) / 16);
    p.Amsg1 = (float*)amsg;
    p.Amsg2 = (float*)(amsg + zb_amsg1);

    p.map1   = (int*)alloc(N_NODES * 4);
    p.map0   = (int*)alloc(N_NODES * 4);
    p.idx1   = (int*)alloc(CAP1 * 4);
    p.idx0   = (int*)alloc(CAP0 * 4);
    p.elist1 = (int*)alloc(ECAP1 * 4);
    p.elist2 = (int*)alloc(ECAP2 * 4);
    p.h0c    = (float*)alloc((size_t)CAP0 * HID * 4);
    p.h1c    = (float*)alloc((size_t)CAP1 * HID * 4);
    p.h2     = (float*)alloc((size_t)BATCH * HID * 4);
    p.w1s    = (unsigned short*)alloc((size_t)IN_DIM * HID * 2);
    p.B1s    = (unsigned short*)alloc((size_t)KCAT * HID * 2);
    p.B2s    = (unsigned short*)alloc((size_t)KCAT * HID * 2);
    (void)ws_size; (void)in_sizes; (void)n_in; (void)out_size;

    // node 1: zero barrier region + ctrs + cnts + flags (~0.9 MB)
    hipMemsetAsync(p.bar, 0, msbytes, stream);

    // co-residency check (pure query; capture-safe, deterministic)
    int occ = 0;
    hipError_t qe = hipOccupancyMaxActiveBlocksPerMultiprocessor(&occ, mega, 256, 0);

    if (qe == hipSuccess && occ >= 1) {
        int nblk = (occ >= 2) ? 512 : 256;   // multiple of 64; all co-resident
        // node 2: the whole pipeline
        mega<<<dim3(nblk), dim3(256), 0, stream>>>(p);
    } else {
        // fallback: 10-kernel chain (known-good)
        const int NB = 256;
        int prep_threads = (IN_DIM * HID) / 8 + 2 * (KCAT * HID) / 8;
        int zp_total = p.nz + prep_threads;
        fb_zero_prep<<<dim3((zp_total + NB - 1) / NB), NB, 0, stream>>>(p);
        fb_mark1c<<<dim3((N_EDGES + NB - 1) / NB), NB, 0, stream>>>(p);
        fb_mark0c<<<dim3((N_EDGES + NB - 1) / NB), NB, 0, stream>>>(p);
        fb_compact<<<dim3((N_NODES + NB - 1) / NB), NB, 0, stream>>>(p);
        fb_gemm1<<<dim3(CAP0 / 64), NB, 0, stream>>>(p);
        fb_scatter1<<<dim3(ECAP1 * 64 / NB), NB, 0, stream>>>(p);
        fb_conv1<<<dim3(CAP1 / 64), NB, 0, stream>>>(p);
        fb_scatter2<<<dim3(ECAP2 * 64 / NB), NB, 0, stream>>>(p);
        fb_conv2<<<dim3(BATCH / 64), NB, 0, stream>>>(p);
        fb_lin2<<<dim3(BATCH / 32), NB, 0, stream>>>(p);
    }
}

// Round 9
// 467.105 us; speedup vs baseline: 1.0096x; 1.0002x over previous
//
#include <hip/hip_runtime.h>

// RGCN pruned to the 2-hop cone of the first 1024 nodes.
// R9: back to the R4 10-kernel chain (409us; every megakernel variant was
// ~467 -- in-kernel barriers cost more than dispatch gaps; fixed ~190us
// harness reset floor identified). This round: GEMM/conv kernels rebuilt
// with NO LDS and NO barriers -- A loaded straight from global into MFMA
// fragments (lane row=l&15, kblock=(l>>4)*8), B pre-permuted so each
// fragment is one coalesced 16B/lane load.

#define N_NODES 100000
#define N_EDGES 400000
#define IN_DIM  768
#define HID     256
#define OUT_DIM 128
#define NREL    3
#define BATCH   1024
#define KCAT    1024   // HID*(NREL+1)
#define MSGW    768    // NREL*HID
#define CAP0    32768  // |S0| ~23K
#define CAP1    8192   // |S1| ~5K
#define ECAP1   32768  // edges into S1 ~20K
#define ECAP2   8192   // edges into S2 ~4.1K

typedef __attribute__((ext_vector_type(8))) short bf16x8;
typedef __attribute__((ext_vector_type(4))) float f32x4;

static __device__ __forceinline__ int imin(int a, int b) { return a < b ? a : b; }

static __device__ __forceinline__ unsigned short f2bf(float f) {
    union { float f; unsigned int u; } v; v.f = f;
    unsigned int r = v.u + 0x7FFFu + ((v.u >> 16) & 1u);   // RNE
    return (unsigned short)(r >> 16);
}

static __device__ __forceinline__ bf16x8 pack8(float4 a0, float4 a1) {
    union { uint4 u; bf16x8 v; } c;
    c.u.x = (unsigned int)f2bf(a0.x) | ((unsigned int)f2bf(a0.y) << 16);
    c.u.y = (unsigned int)f2bf(a0.z) | ((unsigned int)f2bf(a0.w) << 16);
    c.u.z = (unsigned int)f2bf(a1.x) | ((unsigned int)f2bf(a1.y) << 16);
    c.u.w = (unsigned int)f2bf(a1.z) | ((unsigned int)f2bf(a1.w) << 16);
    return c.v;
}

// ---------------- zero + weight prep (fragment-permuted B layout) ----------------
// Bt[((s*16 + f)*64 + l)*8 + j] = bf16( B[s*32 + (l>>4)*8 + j][f*16 + (l&15)] )
// so in the GEMM, lane l of fragment f at K-step s does ONE coalesced 16B load.
#define NP1 ((IN_DIM * HID) / 8)   // 24576 threads for w1t
#define NP2 ((KCAT * HID) / 8)     // 32768 threads for each of B1t/B2t

__global__ __launch_bounds__(256) void zero_prep(
    uint4* __restrict__ zp, int nz,
    const float* __restrict__ W1,
    const float* __restrict__ c1root, const float* __restrict__ c1W,
    const float* __restrict__ c2root, const float* __restrict__ c2W,
    unsigned short* __restrict__ w1t,
    unsigned short* __restrict__ B1t,
    unsigned short* __restrict__ B2t)
{
    int t = blockIdx.x * blockDim.x + threadIdx.x;
    if (t < nz) { zp[t] = make_uint4(0u, 0u, 0u, 0u); return; }
    int u = t - nz;
    if (u < NP1) {
        int s = u >> 10, f = (u >> 6) & 15, l = u & 63;
        int kb = s * 32 + ((l >> 4) << 3);
        int c  = (f << 4) + (l & 15);
        const float* src = W1 + (size_t)kb * HID + c;
        unsigned int p0 = (unsigned int)f2bf(src[0])       | ((unsigned int)f2bf(src[HID])     << 16);
        unsigned int p1 = (unsigned int)f2bf(src[2 * HID]) | ((unsigned int)f2bf(src[3 * HID]) << 16);
        unsigned int p2 = (unsigned int)f2bf(src[4 * HID]) | ((unsigned int)f2bf(src[5 * HID]) << 16);
        unsigned int p3 = (unsigned int)f2bf(src[6 * HID]) | ((unsigned int)f2bf(src[7 * HID]) << 16);
        *(uint4*)&w1t[(size_t)u * 8] = make_uint4(p0, p1, p2, p3);
    } else if (u < NP1 + 2 * NP2) {
        int which2 = (u - NP1) >= NP2;
        int v = (u - NP1) - (which2 ? NP2 : 0);
        const float* root = which2 ? c2root : c1root;
        const float* Wr   = which2 ? c2W : c1W;
        unsigned short* dst = which2 ? B2t : B1t;
        int s = v >> 10, f = (v >> 6) & 15, l = v & 63;
        int kb = s * 32 + ((l >> 4) << 3);
        int c  = (f << 4) + (l & 15);
        unsigned int pk[4];
        #pragma unroll
        for (int q = 0; q < 4; q++) {
            int ka = kb + 2 * q, kbq = ka + 1;
            float va = (ka  < HID) ? root[(size_t)ka  * HID + c] : Wr[(size_t)(ka  - HID) * HID + c];
            float vb = (kbq < HID) ? root[(size_t)kbq * HID + c] : Wr[(size_t)(kbq - HID) * HID + c];
            pk[q] = (unsigned int)f2bf(va) | ((unsigned int)f2bf(vb) << 16);
        }
        *(uint4*)&dst[(size_t)v * 8] = make_uint4(pk[0], pk[1], pk[2], pk[3]);
    }
}

// ---------------- set construction (unchanged, verified R2-R4) ----------------

__global__ void mark1c(const int* __restrict__ ei, int* __restrict__ need1,
                       int* __restrict__ elist2, int* __restrict__ ectr2) {
    int e = blockIdx.x * blockDim.x + threadIdx.x;
    if (e >= N_EDGES) return;
    if (ei[N_EDGES + e] < BATCH) {
        need1[ei[e]] = 1;   // benign same-value race
        int p = atomicAdd(ectr2, 1);
        if (p < ECAP2) elist2[p] = e;
    }
}

__global__ void mark0c(const int* __restrict__ ei, const int* __restrict__ need1,
                       int* __restrict__ need0,
                       int* __restrict__ elist1, int* __restrict__ ectr1) {
    int e = blockIdx.x * blockDim.x + threadIdx.x;
    if (e >= N_EDGES) return;
    int d = ei[N_EDGES + e];
    if (d < BATCH || need1[d]) {
        need0[ei[e]] = 1;
        int p = atomicAdd(ectr1, 1);
        if (p < ECAP1) elist1[p] = e;
    }
}

__global__ void compact_both(const int* __restrict__ need1, const int* __restrict__ need0,
                             int* __restrict__ idx1, int* __restrict__ map1, int* __restrict__ n1ctr,
                             int* __restrict__ idx0, int* __restrict__ map0, int* __restrict__ n0ctr) {
    int i = blockIdx.x * blockDim.x + threadIdx.x;
    if (i >= N_NODES) return;
    int f1 = (i < BATCH) | need1[i];
    int f0 = f1 | need0[i];
    if (f1) {
        int p = atomicAdd(n1ctr, 1);
        if (p < CAP1) { idx1[p] = i; map1[i] = p; } else map1[i] = -1;
    } else map1[i] = -1;
    if (f0) {
        int p = atomicAdd(n0ctr, 1);
        if (p < CAP0) { idx0[p] = i; map0[i] = p; } else map0[i] = -1;
    } else map0[i] = -1;
}

// ---------------- scatter over compacted edge list (unchanged) ----------------

__global__ void scatter_c(const int* __restrict__ ei, const int* __restrict__ et,
                          const int* __restrict__ elist, const int* __restrict__ ectr, int ecap,
                          const int* __restrict__ mapSrc, const int* __restrict__ mapDst,
                          const float* __restrict__ hsrc,
                          float* __restrict__ Amsg, float* __restrict__ cnt,
                          int cntStride) {
    int g = blockIdx.x * blockDim.x + threadIdx.x;
    int ii = g >> 6, lane = g & 63;
    int n = imin(*ectr, ecap);
    if (ii >= n) return;
    int e = elist[ii];
    int d = ei[N_EDGES + e];
    int row = mapDst ? mapDst[d] : d;
    if (row < 0) return;
    int s = mapSrc[ei[e]];
    if (s < 0) return;
    int r = et[e];
    float4 v = *(const float4*)(hsrc + (size_t)s * HID + lane * 4);
    float* dp = Amsg + (size_t)row * MSGW + (size_t)r * HID + lane * 4;
    atomicAdd(dp + 0, v.x);
    atomicAdd(dp + 1, v.y);
    atomicAdd(dp + 2, v.z);
    atomicAdd(dp + 3, v.w);
    if (lane == 0) atomicAdd(cnt + (size_t)r * cntStride + row, 1.0f);
}

// ---------------- linear1: h0c = relu(x[idx0] @ W1 + b1) -- LDS-free MFMA ----------------
// 4 waves x 64-row tile; wave w owns rows w*16..+15, all 256 cols (16 frags).
// A: lane loads x[gr][s*32 + (l>>4)*8 ..+7] (2x float4), converts in-reg.
// B: lane loads w1t fragment (16B coalesced). No LDS, no __syncthreads.
__global__ __launch_bounds__(256) void gemm1_mfma(
    const float* __restrict__ x, const int* __restrict__ idx0,
    const unsigned short* __restrict__ w1t, const float* __restrict__ b1,
    float* __restrict__ h0c, const int* __restrict__ Mptr, int Mcap)
{
    int M = imin(*Mptr, Mcap);
    int bm = blockIdx.x * 64;
    if (bm >= M) return;

    int tid = threadIdx.x;
    int w = tid >> 6, l = tid & 63;
    int l16 = l & 15, lhi = l >> 4;

    int gr = idx0[imin(bm + w * 16 + l16, M - 1)];
    const float* ap = x + (size_t)gr * IN_DIM + lhi * 8;

    f32x4 acc[16];
    #pragma unroll
    for (int i = 0; i < 16; i++) acc[i] = (f32x4)0.0f;

    for (int s = 0; s < IN_DIM / 32; s++) {
        float4 a0 = *(const float4*)(ap + s * 32);
        float4 a1 = *(const float4*)(ap + s * 32 + 4);
        bf16x8 af = pack8(a0, a1);
        const unsigned short* base = w1t + ((size_t)(s * 16) * 64 + l) * 8;
        #pragma unroll
        for (int f = 0; f < 16; f++) {
            bf16x8 bf = *(const bf16x8*)(base + (size_t)f * 512);
            acc[f] = __builtin_amdgcn_mfma_f32_16x16x32_bf16(af, bf, acc[f], 0, 0, 0);
        }
    }

    #pragma unroll
    for (int f = 0; f < 16; f++) {
        int col = f * 16 + l16;
        float bb = b1[col];
        #pragma unroll
        for (int reg = 0; reg < 4; reg++) {
            int row = bm + w * 16 + lhi * 4 + reg;
            if (row < M) h0c[(size_t)row * HID + col] = fmaxf(acc[f][reg] + bb, 0.0f);
        }
    }
}

// ---------------- conv GEMM: C = [root | msg*scale] @ Bcat + bias -- LDS-free ----------------
__global__ __launch_bounds__(256) void conv_mfma(
    const float* __restrict__ hsrc,
    const int* __restrict__ idx, const int* __restrict__ map,
    const float* __restrict__ Amsg,
    const float* __restrict__ cnt, int cntStride,
    const unsigned short* __restrict__ Bt, const float* __restrict__ bias,
    float* __restrict__ Cout, const int* __restrict__ Mptr, int Mcap)
{
    int M = Mptr ? imin(*Mptr, Mcap) : Mcap;
    int bm = blockIdx.x * 64;
    if (bm >= M) return;

    int tid = threadIdx.x;
    int w = tid >> 6, l = tid & 63;
    int l16 = l & 15, lhi = l >> 4;

    int row = imin(bm + w * 16 + l16, M - 1);
    int node = idx ? idx[row] : row;
    int grow = map[node]; if (grow < 0) grow = 0;
    const float* rootp = hsrc + (size_t)grow * HID;
    const float* msgp  = Amsg + (size_t)row * MSGW;
    float sc[NREL];
    #pragma unroll
    for (int r = 0; r < NREL; r++)
        sc[r] = 1.0f / fmaxf(cnt[(size_t)r * cntStride + row], 1.0f);

    int kb = lhi * 8;

    f32x4 acc[16];
    #pragma unroll
    for (int i = 0; i < 16; i++) acc[i] = (f32x4)0.0f;

    for (int s = 0; s < KCAT / 32; s++) {
        int k0 = s * 32 + kb;
        float4 a0, a1;
        if (k0 < HID) {
            a0 = *(const float4*)(rootp + k0);
            a1 = *(const float4*)(rootp + k0 + 4);
        } else {
            float sf = sc[(k0 - HID) >> 8];
            a0 = *(const float4*)(msgp + (k0 - HID));
            a1 = *(const float4*)(msgp + (k0 - HID) + 4);
            a0.x *= sf; a0.y *= sf; a0.z *= sf; a0.w *= sf;
            a1.x *= sf; a1.y *= sf; a1.z *= sf; a1.w *= sf;
        }
        bf16x8 af = pack8(a0, a1);
        const unsigned short* base = Bt + ((size_t)(s * 16) * 64 + l) * 8;
        #pragma unroll
        for (int f = 0; f < 16; f++) {
            bf16x8 bf = *(const bf16x8*)(base + (size_t)f * 512);
            acc[f] = __builtin_amdgcn_mfma_f32_16x16x32_bf16(af, bf, acc[f], 0, 0, 0);
        }
    }

    #pragma unroll
    for (int f = 0; f < 16; f++) {
        int col = f * 16 + l16;
        float bb = bias[col];
        #pragma unroll
        for (int reg = 0; reg < 4; reg++) {
            int r = bm + w * 16 + lhi * 4 + reg;
            if (r < M) Cout[(size_t)r * HID + col] = acc[f][reg] + bb;
        }
    }
}

// ---------------- lin2 + relu + classifier, fused (fp32; unchanged R4) ----------------
__global__ __launch_bounds__(256) void lin2_cls(
    const float* __restrict__ h2, const float* __restrict__ W2,
    const float* __restrict__ b2, const float* __restrict__ Wc,
    const float* __restrict__ bc, float* __restrict__ out)
{
    __shared__ float As[16][36];
    __shared__ float Bs[16][132];

    int tid = threadIdx.x;
    int bm = blockIdx.x * 32;
    int tx = tid & 15, ty = tid >> 4;
    int brow = tid >> 4, bch = tid & 15;

    float acc[2][8] = {};

    for (int k0 = 0; k0 < HID; k0 += 16) {
        if (tid < 128) {
            int arow = tid >> 2, ach = tid & 3;
            float4 av = *(const float4*)(h2 + (size_t)(bm + arow) * HID + k0 + ach * 4);
            As[ach * 4 + 0][arow] = av.x;
            As[ach * 4 + 1][arow] = av.y;
            As[ach * 4 + 2][arow] = av.z;
            As[ach * 4 + 3][arow] = av.w;
        }
        const float* bp = W2 + (size_t)(k0 + brow) * OUT_DIM;
        *(float4*)&Bs[brow][bch * 4]      = *(const float4*)(bp + bch * 4);
        *(float4*)&Bs[brow][64 + bch * 4] = *(const float4*)(bp + 64 + bch * 4);
        __syncthreads();
        #pragma unroll
        for (int k = 0; k < 16; k++) {
            float a0 = As[k][ty * 2], a1 = As[k][ty * 2 + 1];
            float4 b0 = *(const float4*)&Bs[k][tx * 8];
            float4 b1 = *(const float4*)&Bs[k][tx * 8 + 4];
            acc[0][0] += a0 * b0.x; acc[0][1] += a0 * b0.y; acc[0][2] += a0 * b0.z; acc[0][3] += a0 * b0.w;
            acc[0][4] += a0 * b1.x; acc[0][5] += a0 * b1.y; acc[0][6] += a0 * b1.z; acc[0][7] += a0 * b1.w;
            acc[1][0] += a1 * b0.x; acc[1][1] += a1 * b0.y; acc[1][2] += a1 * b0.z; acc[1][3] += a1 * b0.w;
            acc[1][4] += a1 * b1.x; acc[1][5] += a1 * b1.y; acc[1][6] += a1 * b1.z; acc[1][7] += a1 * b1.w;
        }
        __syncthreads();
    }

    float s0[2] = {0.f, 0.f}, s1[2] = {0.f, 0.f};
    #pragma unroll
    for (int j = 0; j < 8; j++) {
        int col = tx * 8 + j;
        float w0 = Wc[col * 2 + 0], w1 = Wc[col * 2 + 1];
        float bb = b2[col];
        #pragma unroll
        for (int i = 0; i < 2; i++) {
            float h = fmaxf(acc[i][j] + bb, 0.0f);
            s0[i] += h * w0;
            s1[i] += h * w1;
        }
    }
    #pragma unroll
    for (int o = 1; o <= 8; o <<= 1) {
        #pragma unroll
        for (int i = 0; i < 2; i++) {
            s0[i] += __shfl_xor(s0[i], o);
            s1[i] += __shfl_xor(s1[i], o);
        }
    }
    if (tx == 0) {
        #pragma unroll
        for (int i = 0; i < 2; i++) {
            int row = bm + ty * 2 + i;
            out[row * 2 + 0] = s0[i] + bc[0];
            out[row * 2 + 1] = s1[i] + bc[1];
        }
    }
}

// ---------------- host ----------------

extern "C" void kernel_launch(void* const* d_in, const int* in_sizes, int n_in,
                              void* d_out, int out_size, void* d_ws, size_t ws_size,
                              hipStream_t stream) {
    const float* x      = (const float*)d_in[0];
    const int*   ei     = (const int*)d_in[1];
    const int*   et     = (const int*)d_in[2];
    const float* W1     = (const float*)d_in[4];
    const float* b1     = (const float*)d_in[5];
    const float* c1W    = (const float*)d_in[6];
    const float* c1root = (const float*)d_in[7];
    const float* c1bias = (const float*)d_in[8];
    const float* c2W    = (const float*)d_in[9];
    const float* c2root = (const float*)d_in[10];
    const float* c2bias = (const float*)d_in[11];
    const float* W2     = (const float*)d_in[12];
    const float* b2     = (const float*)d_in[13];
    const float* Wc     = (const float*)d_in[14];
    const float* bc     = (const float*)d_in[15];
    float* out = (float*)d_out;

    char* ws = (char*)d_ws;
    size_t off = 0;
    auto alloc = [&](size_t bytes) -> char* {
        char* p = ws + off;
        off = (off + bytes + 255) & ~(size_t)255;
        return p;
    };

    // --- zero block (zeroed by zero_prep): ctrs | cnt1 | cnt2 | need1 | need0 | Amsg1 | Amsg2 ---
    size_t zb_ctr   = 16;
    size_t zb_cnt1  = (size_t)NREL * CAP1 * 4;
    size_t zb_cnt2  = (size_t)NREL * BATCH * 4;
    size_t zb_need  = (size_t)N_NODES * 4;
    size_t zb_amsg1 = (size_t)CAP1 * MSGW * 4;
    size_t zb_amsg2 = (size_t)BATCH * MSGW * 4;
    size_t zbytes = zb_ctr + zb_cnt1 + zb_cnt2 + 2 * zb_need + zb_amsg1 + zb_amsg2;
    char* zblock = alloc(zbytes);
    int*   n1ctr = (int*)zblock;
    int*   n0ctr = n1ctr + 1;
    int*   ectr1 = n1ctr + 2;
    int*   ectr2 = n1ctr + 3;
    float* cnt1  = (float*)(zblock + zb_ctr);
    float* cnt2  = (float*)(zblock + zb_ctr + zb_cnt1);
    int*   need1 = (int*)(zblock + zb_ctr + zb_cnt1 + zb_cnt2);
    int*   need0 = (int*)((char*)need1 + zb_need);
    float* Amsg1 = (float*)((char*)need0 + zb_need);
    float* Amsg2 = (float*)((char*)Amsg1 + zb_amsg1);

    int* map1  = (int*)alloc(N_NODES * 4);
    int* map0  = (int*)alloc(N_NODES * 4);
    int* idx1  = (int*)alloc(CAP1 * 4);
    int* idx0  = (int*)alloc(CAP0 * 4);
    int* elist1 = (int*)alloc(ECAP1 * 4);
    int* elist2 = (int*)alloc(ECAP2 * 4);
    float* h0c = (float*)alloc((size_t)CAP0 * HID * 4);
    float* h1c = (float*)alloc((size_t)CAP1 * HID * 4);
    float* h2  = (float*)alloc((size_t)BATCH * HID * 4);
    unsigned short* w1t = (unsigned short*)alloc((size_t)IN_DIM * HID * 2);
    unsigned short* B1t = (unsigned short*)alloc((size_t)KCAT * HID * 2);
    unsigned short* B2t = (unsigned short*)alloc((size_t)KCAT * HID * 2);
    (void)ws_size; (void)in_sizes; (void)n_in; (void)out_size;

    const int NB = 256;
    dim3 nodeGrid((N_NODES + NB - 1) / NB);
    dim3 edgeGrid((N_EDGES + NB - 1) / NB);

    int nz = (int)((zbytes + 15) / 16);
    int zp_total = nz + NP1 + 2 * NP2;

    // 1: zero accum block + fragment-permuted bf16 weight prep
    zero_prep<<<dim3((zp_total + NB - 1) / NB), NB, 0, stream>>>(
        (uint4*)zblock, nz, W1, c1root, c1W, c2root, c2W, w1t, B1t, B2t);
    // 2-4: dependency cone + edge lists + both compactions
    mark1c<<<edgeGrid, NB, 0, stream>>>(ei, need1, elist2, ectr2);
    mark0c<<<edgeGrid, NB, 0, stream>>>(ei, need1, need0, elist1, ectr1);
    compact_both<<<nodeGrid, NB, 0, stream>>>(need1, need0, idx1, map1, n1ctr, idx0, map0, n0ctr);
    // 5: h0c = relu(x[S0] @ W1 + b1)
    gemm1_mfma<<<dim3(CAP0 / 64), NB, 0, stream>>>(x, idx0, w1t, b1, h0c, n0ctr, CAP0);
    // 6-7: conv1
    scatter_c<<<dim3(ECAP1 * 64 / NB), NB, 0, stream>>>(ei, et, elist1, ectr1, ECAP1,
                                                        map0, map1, h0c, Amsg1, cnt1, CAP1);
    conv_mfma<<<dim3(CAP1 / 64), NB, 0, stream>>>(h0c, idx1, map0, Amsg1, cnt1, CAP1,
                                                  B1t, c1bias, h1c, n1ctr, CAP1);
    // 8-9: conv2 (rows = node ids 0..1023)
    scatter_c<<<dim3(ECAP2 * 64 / NB), NB, 0, stream>>>(ei, et, elist2, ectr2, ECAP2,
                                                        map1, nullptr, h1c, Amsg2, cnt2, BATCH);
    conv_mfma<<<dim3(BATCH / 64), NB, 0, stream>>>(h1c, nullptr, map1, Amsg2, cnt2, BATCH,
                                                   B2t, c2bias, h2, nullptr, BATCH);
    // 10: logits = relu(h2 @ W2 + b2) @ Wc + bc
    lin2_cls<<<dim3(BATCH / 32), NB, 0, stream>>>(h2, W2, b2, Wc, bc, out);
}

// Round 10
// 408.535 us; speedup vs baseline: 1.1543x; 1.1434x over previous
//
#include <hip/hip_runtime.h>

// RGCN pruned to the 2-hop cone of the first 1024 nodes.
// R10: CONTROL EXPERIMENT -- exact resubmission of R4's kernel (best wall
// measurement, 408.6us). Every round since R6 measured 467-471 regardless of
// implementation (megakernel slow/fast barriers, plain chain, LDS-free GEMMs),
// while R3/R4 measured 409-412. This run discriminates: ~410 => R9's LDS-free
// GEMMs were a real regression and this config is the champion; ~467 => the
// harness/machine wall floor shifted and sub-60us implementation differences
// are unmeasurable.

#define N_NODES 100000
#define N_EDGES 400000
#define IN_DIM  768
#define HID     256
#define OUT_DIM 128
#define NREL    3
#define BATCH   1024
#define KCAT    1024   // HID*(NREL+1)
#define MSGW    768    // NREL*HID
#define CAP0    32768  // |S0| ~23K
#define CAP1    8192   // |S1| ~5K
#define ECAP1   32768  // edges into S1 ~20K
#define ECAP2   8192   // edges into S2 ~4.1K

typedef __attribute__((ext_vector_type(8))) short bf16x8;
typedef __attribute__((ext_vector_type(4))) float f32x4;

static __device__ __forceinline__ int imin(int a, int b) { return a < b ? a : b; }

static __device__ __forceinline__ unsigned short f2bf(float f) {
    union { float f; unsigned int u; } v; v.f = f;
    unsigned int r = v.u + 0x7FFFu + ((v.u >> 16) & 1u);   // RNE
    return (unsigned short)(r >> 16);
}

// ---------------- zero (custom fill) + weight prep, one kernel ----------------
__global__ __launch_bounds__(256) void zero_prep(
    uint4* __restrict__ zp, int nz,
    const float* __restrict__ W1,
    const float* __restrict__ c1root, const float* __restrict__ c1W,
    const float* __restrict__ c2root, const float* __restrict__ c2W,
    unsigned short* __restrict__ w1s,
    unsigned short* __restrict__ B1s,
    unsigned short* __restrict__ B2s)
{
    int t = blockIdx.x * blockDim.x + threadIdx.x;
    if (t < nz) { zp[t] = make_uint4(0u, 0u, 0u, 0u); return; }
    int u = t - nz;
    const int P1 = (IN_DIM * HID) / 8;   // 24576
    const int P2 = (KCAT * HID) / 8;     // 32768
    unsigned int pk[4];
    if (u < P1) {
        int base = u * 8;
        int j0 = base & 31, c = (base >> 5) & 255, s = base >> 13;
        #pragma unroll
        for (int q = 0; q < 4; q++) {
            unsigned short lo = f2bf(W1[((s * 32 + j0 + 2 * q) << 8) + c]);
            unsigned short hi = f2bf(W1[((s * 32 + j0 + 2 * q + 1) << 8) + c]);
            pk[q] = (unsigned int)lo | ((unsigned int)hi << 16);
        }
        *(uint4*)&w1s[base] = make_uint4(pk[0], pk[1], pk[2], pk[3]);
    } else if (u < P1 + 2 * P2) {
        int which2 = (u - P1) >= P2;
        const float* root = which2 ? c2root : c1root;
        const float* Wr   = which2 ? c2W : c1W;
        unsigned short* dst = which2 ? B2s : B1s;
        int base = ((u - P1) - (which2 ? P2 : 0)) * 8;
        int j0 = base & 31, c = (base >> 5) & 255, s = base >> 13;
        int k0 = s * 32 + j0;
        #pragma unroll
        for (int q = 0; q < 4; q++) {
            int ka = k0 + 2 * q, kb = ka + 1;
            float va = (ka < HID) ? root[(ka << 8) + c] : Wr[((ka - HID) << 8) + c];
            float vb = (kb < HID) ? root[(kb << 8) + c] : Wr[((kb - HID) << 8) + c];
            pk[q] = (unsigned int)f2bf(va) | ((unsigned int)f2bf(vb) << 16);
        }
        *(uint4*)&dst[base] = make_uint4(pk[0], pk[1], pk[2], pk[3]);
    }
}

// ---------------- set construction ----------------

__global__ void mark1c(const int* __restrict__ ei, int* __restrict__ need1,
                       int* __restrict__ elist2, int* __restrict__ ectr2) {
    int e = blockIdx.x * blockDim.x + threadIdx.x;
    if (e >= N_EDGES) return;
    if (ei[N_EDGES + e] < BATCH) {
        need1[ei[e]] = 1;   // benign same-value race
        int p = atomicAdd(ectr2, 1);
        if (p < ECAP2) elist2[p] = e;
    }
}

__global__ void mark0c(const int* __restrict__ ei, const int* __restrict__ need1,
                       int* __restrict__ need0,
                       int* __restrict__ elist1, int* __restrict__ ectr1) {
    int e = blockIdx.x * blockDim.x + threadIdx.x;
    if (e >= N_EDGES) return;
    int d = ei[N_EDGES + e];
    if (d < BATCH || need1[d]) {
        need0[ei[e]] = 1;
        int p = atomicAdd(ectr1, 1);
        if (p < ECAP1) elist1[p] = e;
    }
}

__global__ void compact_both(const int* __restrict__ need1, const int* __restrict__ need0,
                             int* __restrict__ idx1, int* __restrict__ map1, int* __restrict__ n1ctr,
                             int* __restrict__ idx0, int* __restrict__ map0, int* __restrict__ n0ctr) {
    int i = blockIdx.x * blockDim.x + threadIdx.x;
    if (i >= N_NODES) return;
    int f1 = (i < BATCH) | need1[i];
    int f0 = f1 | need0[i];
    if (f1) {
        int p = atomicAdd(n1ctr, 1);
        if (p < CAP1) { idx1[p] = i; map1[i] = p; } else map1[i] = -1;
    } else map1[i] = -1;
    if (f0) {
        int p = atomicAdd(n0ctr, 1);
        if (p < CAP0) { idx0[p] = i; map0[i] = p; } else map0[i] = -1;
    } else map0[i] = -1;
}

// ---------------- scatter over compacted edge list ----------------
__global__ void scatter_c(const int* __restrict__ ei, const int* __restrict__ et,
                          const int* __restrict__ elist, const int* __restrict__ ectr, int ecap,
                          const int* __restrict__ mapSrc, const int* __restrict__ mapDst,
                          const float* __restrict__ hsrc,
                          float* __restrict__ Amsg, float* __restrict__ cnt,
                          int cntStride) {
    int g = blockIdx.x * blockDim.x + threadIdx.x;
    int ii = g >> 6, lane = g & 63;
    int n = imin(*ectr, ecap);
    if (ii >= n) return;
    int e = elist[ii];
    int d = ei[N_EDGES + e];
    int row = mapDst ? mapDst[d] : d;
    if (row < 0) return;
    int s = mapSrc[ei[e]];
    if (s < 0) return;
    int r = et[e];
    float4 v = *(const float4*)(hsrc + (size_t)s * HID + lane * 4);
    float* dp = Amsg + (size_t)row * MSGW + (size_t)r * HID + lane * 4;
    atomicAdd(dp + 0, v.x);
    atomicAdd(dp + 1, v.y);
    atomicAdd(dp + 2, v.z);
    atomicAdd(dp + 3, v.w);
    if (lane == 0) atomicAdd(cnt + (size_t)r * cntStride + row, 1.0f);
}

// ---------------- linear1: h0c = relu(x[idx0] @ W1 + b1), bf16 MFMA ----------------
__global__ __launch_bounds__(256) void gemm1_mfma(
    const float* __restrict__ x, const int* __restrict__ idx0,
    const unsigned short* __restrict__ w1s, const float* __restrict__ b1,
    float* __restrict__ h0c, const int* __restrict__ Mptr, int Mcap)
{
    int M = imin(*Mptr, Mcap);
    int bm = blockIdx.x * 64;
    if (bm >= M) return;

    __shared__ unsigned short As[64][40];
    __shared__ unsigned short Bs[256][40];

    int tid = threadIdx.x;
    int w = tid >> 6, lane = tid & 63;
    int l16 = lane & 15, lhi = lane >> 4;

    int ar = tid >> 2, ac = tid & 3;
    int gr = idx0[imin(bm + ar, M - 1)];
    const float* aptr = x + (size_t)gr * IN_DIM + ac * 8;

    f32x4 acc[16];
    #pragma unroll
    for (int i = 0; i < 16; i++) acc[i] = (f32x4)0.0f;

    for (int k0 = 0; k0 < IN_DIM; k0 += 32) {
        float4 a0 = *(const float4*)(aptr + k0);
        float4 a1 = *(const float4*)(aptr + k0 + 4);
        unsigned int p0 = (unsigned int)f2bf(a0.x) | ((unsigned int)f2bf(a0.y) << 16);
        unsigned int p1 = (unsigned int)f2bf(a0.z) | ((unsigned int)f2bf(a0.w) << 16);
        unsigned int p2 = (unsigned int)f2bf(a1.x) | ((unsigned int)f2bf(a1.y) << 16);
        unsigned int p3 = (unsigned int)f2bf(a1.z) | ((unsigned int)f2bf(a1.w) << 16);
        *(uint4*)&As[ar][ac * 8] = make_uint4(p0, p1, p2, p3);

        const uint4* bsrc = (const uint4*)(w1s + ((size_t)(k0 >> 5) * 256 + tid) * 32);
        int bswz = (tid >> 3) & 3;
        uint4 b0 = bsrc[0], b1v = bsrc[1], b2 = bsrc[2], b3 = bsrc[3];
        *(uint4*)&Bs[tid][(0 ^ bswz) * 8] = b0;
        *(uint4*)&Bs[tid][(1 ^ bswz) * 8] = b1v;
        *(uint4*)&Bs[tid][(2 ^ bswz) * 8] = b2;
        *(uint4*)&Bs[tid][(3 ^ bswz) * 8] = b3;
        __syncthreads();

        bf16x8 af = *(bf16x8*)&As[w * 16 + l16][lhi * 8];
        #pragma unroll
        for (int f = 0; f < 16; f++) {
            int col = f * 16 + l16;
            bf16x8 bf = *(bf16x8*)&Bs[col][(lhi ^ ((col >> 3) & 3)) * 8];
            acc[f] = __builtin_amdgcn_mfma_f32_16x16x32_bf16(af, bf, acc[f], 0, 0, 0);
        }
        __syncthreads();
    }

    #pragma unroll
    for (int f = 0; f < 16; f++) {
        int col = f * 16 + l16;
        float bb = b1[col];
        #pragma unroll
        for (int reg = 0; reg < 4; reg++) {
            int row = bm + w * 16 + lhi * 4 + reg;
            if (row < M) h0c[(size_t)row * HID + col] = fmaxf(acc[f][reg] + bb, 0.0f);
        }
    }
}

// ---------------- conv GEMM: C = [root | msg*scale] @ Bcat + bias, bf16 MFMA ----------------
__global__ __launch_bounds__(256) void conv_mfma(
    const float* __restrict__ hsrc,
    const int* __restrict__ idx, const int* __restrict__ map,
    const float* __restrict__ Amsg,
    const float* __restrict__ cnt, int cntStride,
    const unsigned short* __restrict__ Bt, const float* __restrict__ bias,
    float* __restrict__ Cout, const int* __restrict__ Mptr, int Mcap)
{
    int M = Mptr ? imin(*Mptr, Mcap) : Mcap;
    int bm = blockIdx.x * 64;
    if (bm >= M) return;

    __shared__ unsigned short As[64][40];
    __shared__ unsigned short Bs[256][40];

    int tid = threadIdx.x;
    int w = tid >> 6, lane = tid & 63;
    int l16 = lane & 15, lhi = lane >> 4;

    int ar = tid >> 2, ac = tid & 3;
    int row = imin(bm + ar, M - 1);
    int node = idx ? idx[row] : row;
    int grow = map[node]; if (grow < 0) grow = 0;
    const float* rootp = hsrc + (size_t)grow * HID + ac * 8;
    const float* msgp  = Amsg + (size_t)row * MSGW + ac * 8;
    float sc[NREL];
    #pragma unroll
    for (int r = 0; r < NREL; r++)
        sc[r] = 1.0f / fmaxf(cnt[(size_t)r * cntStride + row], 1.0f);

    f32x4 acc[16];
    #pragma unroll
    for (int i = 0; i < 16; i++) acc[i] = (f32x4)0.0f;

    for (int k0 = 0; k0 < KCAT; k0 += 32) {
        float4 a0, a1;
        if (k0 < HID) {
            a0 = *(const float4*)(rootp + k0);
            a1 = *(const float4*)(rootp + k0 + 4);
        } else {
            float s = sc[(k0 - HID) >> 8];
            a0 = *(const float4*)(msgp + (k0 - HID));
            a1 = *(const float4*)(msgp + (k0 - HID) + 4);
            a0.x *= s; a0.y *= s; a0.z *= s; a0.w *= s;
            a1.x *= s; a1.y *= s; a1.z *= s; a1.w *= s;
        }
        unsigned int p0 = (unsigned int)f2bf(a0.x) | ((unsigned int)f2bf(a0.y) << 16);
        unsigned int p1 = (unsigned int)f2bf(a0.z) | ((unsigned int)f2bf(a0.w) << 16);
        unsigned int p2 = (unsigned int)f2bf(a1.x) | ((unsigned int)f2bf(a1.y) << 16);
        unsigned int p3 = (unsigned int)f2bf(a1.z) | ((unsigned int)f2bf(a1.w) << 16);
        *(uint4*)&As[ar][ac * 8] = make_uint4(p0, p1, p2, p3);

        const uint4* bsrc = (const uint4*)(Bt + ((size_t)(k0 >> 5) * 256 + tid) * 32);
        int bswz = (tid >> 3) & 3;
        uint4 b0 = bsrc[0], b1v = bsrc[1], b2 = bsrc[2], b3 = bsrc[3];
        *(uint4*)&Bs[tid][(0 ^ bswz) * 8] = b0;
        *(uint4*)&Bs[tid][(1 ^ bswz) * 8] = b1v;
        *(uint4*)&Bs[tid][(2 ^ bswz) * 8] = b2;
        *(uint4*)&Bs[tid][(3 ^ bswz) * 8] = b3;
        __syncthreads();

        bf16x8 af = *(bf16x8*)&As[w * 16 + l16][lhi * 8];
        #pragma unroll
        for (int f = 0; f < 16; f++) {
            int col = f * 16 + l16;
            bf16x8 bf = *(bf16x8*)&Bs[col][(lhi ^ ((col >> 3) & 3)) * 8];
            acc[f] = __builtin_amdgcn_mfma_f32_16x16x32_bf16(af, bf, acc[f], 0, 0, 0);
        }
        __syncthreads();
    }

    #pragma unroll
    for (int f = 0; f < 16; f++) {
        int col = f * 16 + l16;
        float bb = bias[col];
        #pragma unroll
        for (int reg = 0; reg < 4; reg++) {
            int r = bm + w * 16 + lhi * 4 + reg;
            if (r < M) Cout[(size_t)r * HID + col] = acc[f][reg] + bb;
        }
    }
}

// ---------------- lin2 + relu + classifier, fused (fp32) ----------------
__global__ __launch_bounds__(256) void lin2_cls(
    const float* __restrict__ h2, const float* __restrict__ W2,
    const float* __restrict__ b2, const float* __restrict__ Wc,
    const float* __restrict__ bc, float* __restrict__ out)
{
    __shared__ float As[16][36];
    __shared__ float Bs[16][132];

    int tid = threadIdx.x;
    int bm = blockIdx.x * 32;
    int tx = tid & 15, ty = tid >> 4;
    int brow = tid >> 4, bch = tid & 15;

    float acc[2][8] = {};

    for (int k0 = 0; k0 < HID; k0 += 16) {
        if (tid < 128) {
            int arow = tid >> 2, ach = tid & 3;
            float4 av = *(const float4*)(h2 + (size_t)(bm + arow) * HID + k0 + ach * 4);
            As[ach * 4 + 0][arow] = av.x;
            As[ach * 4 + 1][arow] = av.y;
            As[ach * 4 + 2][arow] = av.z;
            As[ach * 4 + 3][arow] = av.w;
        }
        const float* bp = W2 + (size_t)(k0 + brow) * OUT_DIM;
        *(float4*)&Bs[brow][bch * 4]      = *(const float4*)(bp + bch * 4);
        *(float4*)&Bs[brow][64 + bch * 4] = *(const float4*)(bp + 64 + bch * 4);
        __syncthreads();
        #pragma unroll
        for (int k = 0; k < 16; k++) {
            float a0 = As[k][ty * 2], a1 = As[k][ty * 2 + 1];
            float4 b0 = *(const float4*)&Bs[k][tx * 8];
            float4 b1 = *(const float4*)&Bs[k][tx * 8 + 4];
            acc[0][0] += a0 * b0.x; acc[0][1] += a0 * b0.y; acc[0][2] += a0 * b0.z; acc[0][3] += a0 * b0.w;
            acc[0][4] += a0 * b1.x; acc[0][5] += a0 * b1.y; acc[0][6] += a0 * b1.z; acc[0][7] += a0 * b1.w;
            acc[1][0] += a1 * b0.x; acc[1][1] += a1 * b0.y; acc[1][2] += a1 * b0.z; acc[1][3] += a1 * b0.w;
            acc[1][4] += a1 * b1.x; acc[1][5] += a1 * b1.y; acc[1][6] += a1 * b1.z; acc[1][7] += a1 * b1.w;
        }
        __syncthreads();
    }

    float s0[2] = {0.f, 0.f}, s1[2] = {0.f, 0.f};
    #pragma unroll
    for (int j = 0; j < 8; j++) {
        int col = tx * 8 + j;
        float w0 = Wc[col * 2 + 0], w1 = Wc[col * 2 + 1];
        float bb = b2[col];
        #pragma unroll
        for (int i = 0; i < 2; i++) {
            float h = fmaxf(acc[i][j] + bb, 0.0f);
            s0[i] += h * w0;
            s1[i] += h * w1;
        }
    }
    #pragma unroll
    for (int o = 1; o <= 8; o <<= 1) {
        #pragma unroll
        for (int i = 0; i < 2; i++) {
            s0[i] += __shfl_xor(s0[i], o);
            s1[i] += __shfl_xor(s1[i], o);
        }
    }
    if (tx == 0) {
        #pragma unroll
        for (int i = 0; i < 2; i++) {
            int row = bm + ty * 2 + i;
            out[row * 2 + 0] = s0[i] + bc[0];
            out[row * 2 + 1] = s1[i] + bc[1];
        }
    }
}

// ---------------- host ----------------

extern "C" void kernel_launch(void* const* d_in, const int* in_sizes, int n_in,
                              void* d_out, int out_size, void* d_ws, size_t ws_size,
                              hipStream_t stream) {
    const float* x      = (const float*)d_in[0];
    const int*   ei     = (const int*)d_in[1];
    const int*   et     = (const int*)d_in[2];
    const float* W1     = (const float*)d_in[4];
    const float* b1     = (const float*)d_in[5];
    const float* c1W    = (const float*)d_in[6];
    const float* c1root = (const float*)d_in[7];
    const float* c1bias = (const float*)d_in[8];
    const float* c2W    = (const float*)d_in[9];
    const float* c2root = (const float*)d_in[10];
    const float* c2bias = (const float*)d_in[11];
    const float* W2     = (const float*)d_in[12];
    const float* b2     = (const float*)d_in[13];
    const float* Wc     = (const float*)d_in[14];
    const float* bc     = (const float*)d_in[15];
    float* out = (float*)d_out;

    char* ws = (char*)d_ws;
    size_t off = 0;
    auto alloc = [&](size_t bytes) -> char* {
        char* p = ws + off;
        off = (off + bytes + 255) & ~(size_t)255;
        return p;
    };

    // --- zero block: ctrs | cnt1 | cnt2 | need1 | need0 | Amsg1 | Amsg2 ---
    size_t zb_ctr   = 16;
    size_t zb_cnt1  = (size_t)NREL * CAP1 * 4;
    size_t zb_cnt2  = (size_t)NREL * BATCH * 4;
    size_t zb_need  = (size_t)N_NODES * 4;
    size_t zb_amsg1 = (size_t)CAP1 * MSGW * 4;
    size_t zb_amsg2 = (size_t)BATCH * MSGW * 4;
    size_t zbytes = zb_ctr + zb_cnt1 + zb_cnt2 + 2 * zb_need + zb_amsg1 + zb_amsg2;
    char* zblock = alloc(zbytes);
    int*   n1ctr = (int*)zblock;
    int*   n0ctr = n1ctr + 1;
    int*   ectr1 = n1ctr + 2;
    int*   ectr2 = n1ctr + 3;
    float* cnt1  = (float*)(zblock + zb_ctr);
    float* cnt2  = (float*)(zblock + zb_ctr + zb_cnt1);
    int*   need1 = (int*)(zblock + zb_ctr + zb_cnt1 + zb_cnt2);
    int*   need0 = (int*)((char*)need1 + zb_need);
    float* Amsg1 = (float*)((char*)need0 + zb_need);
    float* Amsg2 = (float*)((char*)Amsg1 + zb_amsg1);

    int* map1  = (int*)alloc(N_NODES * 4);
    int* map0  = (int*)alloc(N_NODES * 4);
    int* idx1  = (int*)alloc(CAP1 * 4);
    int* idx0  = (int*)alloc(CAP0 * 4);
    int* elist1 = (int*)alloc(ECAP1 * 4);
    int* elist2 = (int*)alloc(ECAP2 * 4);
    float* h0c = (float*)alloc((size_t)CAP0 * HID * 4);
    float* h1c = (float*)alloc((size_t)CAP1 * HID * 4);
    float* h2  = (float*)alloc((size_t)BATCH * HID * 4);
    unsigned short* w1s = (unsigned short*)alloc((size_t)IN_DIM * HID * 2);
    unsigned short* B1s = (unsigned short*)alloc((size_t)KCAT * HID * 2);
    unsigned short* B2s = (unsigned short*)alloc((size_t)KCAT * HID * 2);
    (void)ws_size; (void)in_sizes; (void)n_in; (void)out_size;

    const int NB = 256;
    dim3 nodeGrid((N_NODES + NB - 1) / NB);
    dim3 edgeGrid((N_EDGES + NB - 1) / NB);

    int nz = (int)((zbytes + 15) / 16);
    int prep_threads = (IN_DIM * HID) / 8 + 2 * (KCAT * HID) / 8;
    int zp_total = nz + prep_threads;

    // 1: zero + weight prep
    zero_prep<<<dim3((zp_total + NB - 1) / NB), NB, 0, stream>>>(
        (uint4*)zblock, nz, W1, c1root, c1W, c2root, c2W, w1s, B1s, B2s);
    // 2-4: dependency cone + edge lists + both compactions
    mark1c<<<edgeGrid, NB, 0, stream>>>(ei, need1, elist2, ectr2);
    mark0c<<<edgeGrid, NB, 0, stream>>>(ei, need1, need0, elist1, ectr1);
    compact_both<<<nodeGrid, NB, 0, stream>>>(need1, need0, idx1, map1, n1ctr, idx0, map0, n0ctr);
    // 5: h0c = relu(x[S0] @ W1 + b1)
    gemm1_mfma<<<dim3(CAP0 / 64), NB, 0, stream>>>(x, idx0, w1s, b1, h0c, n0ctr, CAP0);
    // 6-7: conv1
    scatter_c<<<dim3(ECAP1 * 64 / NB), NB, 0, stream>>>(ei, et, elist1, ectr1, ECAP1,
                                                        map0, map1, h0c, Amsg1, cnt1, CAP1);
    conv_mfma<<<dim3(CAP1 / 64), NB, 0, stream>>>(h0c, idx1, map0, Amsg1, cnt1, CAP1,
                                                  B1s, c1bias, h1c, n1ctr, CAP1);
    // 8-9: conv2 (rows = node ids 0..1023)
    scatter_c<<<dim3(ECAP2 * 64 / NB), NB, 0, stream>>>(ei, et, elist2, ectr2, ECAP2,
                                                        map1, nullptr, h1c, Amsg2, cnt2, BATCH);
    conv_mfma<<<dim3(BATCH / 64), NB, 0, stream>>>(h1c, nullptr, map1, Amsg2, cnt2, BATCH,
                                                   B2s, c2bias, h2, nullptr, BATCH);
    // 10: logits = relu(h2 @ W2 + b2) @ Wc + bc
    lin2_cls<<<dim3(BATCH / 32), NB, 0, stream>>>(h2, W2, b2, Wc, bc, out);
}

// Round 11
// 379.376 us; speedup vs baseline: 1.2430x; 1.0769x over previous
//
#include <hip/hip_runtime.h>

// RGCN pruned to the 2-hop cone of the first 1024 nodes.
// R11: 9 graph nodes. R10 control confirmed champion (408.5us, reproducible
// to 0.1us). This round: (1) small memset node for flags/ctrs lets mark1c
// fuse into prep+Amsg-zero; (2) compactS1 fuses into mark0c; (3) lin2+relu+
// classifier fused into conv2's epilogue (conv2 rows are block-local): h2
// tile staged in LDS as bf16, one extra MFMA pass vs W2 fragments, 16-lane
// shuffle reduce for the 2 logits.

#define N_NODES 100000
#define N_EDGES 400000
#define IN_DIM  768
#define HID     256
#define OUT_DIM 128
#define NREL    3
#define BATCH   1024
#define KCAT    1024   // HID*(NREL+1)
#define MSGW    768    // NREL*HID
#define CAP0    32768  // |S0| ~23K
#define CAP1    8192   // |S1| ~5K
#define ECAP1   32768  // edges into S1 ~20K
#define ECAP2   8192   // edges into S2 ~4.1K

typedef __attribute__((ext_vector_type(8))) short bf16x8;
typedef __attribute__((ext_vector_type(4))) float f32x4;

static __device__ __forceinline__ int imin(int a, int b) { return a < b ? a : b; }

static __device__ __forceinline__ unsigned short f2bf(float f) {
    union { float f; unsigned int u; } v; v.f = f;
    unsigned int r = v.u + 0x7FFFu + ((v.u >> 16) & 1u);   // RNE
    return (unsigned short)(r >> 16);
}

#define P1n  ((IN_DIM * HID) / 8)    // 24576 w1s threads
#define P2n  ((KCAT * HID) / 8)      // 32768 per B1s/B2s
#define PW2n ((HID * OUT_DIM) / 8)   // 4096 W2t threads

// ---------------- N1: Amsg zero + all weight prep + mark1c ----------------
// (flags/ctrs/cnts zeroed by the preceding small memset node, so the mark
//  range here can safely use need1/ectr2.)
__global__ __launch_bounds__(256) void prep_mark1(
    uint4* __restrict__ zp, int nzA,
    const float* __restrict__ W1,
    const float* __restrict__ c1root, const float* __restrict__ c1W,
    const float* __restrict__ c2root, const float* __restrict__ c2W,
    const float* __restrict__ W2,
    unsigned short* __restrict__ w1s,
    unsigned short* __restrict__ B1s,
    unsigned short* __restrict__ B2s,
    unsigned short* __restrict__ W2t,
    const int* __restrict__ ei, int* __restrict__ need1,
    int* __restrict__ elist2, int* __restrict__ ectr2)
{
    int t = blockIdx.x * blockDim.x + threadIdx.x;
    if (t < nzA) { zp[t] = make_uint4(0u, 0u, 0u, 0u); return; }
    int u = t - nzA;
    if (u < P1n) {
        int base = u * 8;
        int j0 = base & 31, c = (base >> 5) & 255, s = base >> 13;
        unsigned int pk[4];
        #pragma unroll
        for (int q = 0; q < 4; q++) {
            unsigned short lo = f2bf(W1[((s * 32 + j0 + 2 * q) << 8) + c]);
            unsigned short hi = f2bf(W1[((s * 32 + j0 + 2 * q + 1) << 8) + c]);
            pk[q] = (unsigned int)lo | ((unsigned int)hi << 16);
        }
        *(uint4*)&w1s[base] = make_uint4(pk[0], pk[1], pk[2], pk[3]);
        return;
    }
    u -= P1n;
    if (u < 2 * P2n) {
        int which2 = u >= P2n;
        const float* root = which2 ? c2root : c1root;
        const float* Wr   = which2 ? c2W : c1W;
        unsigned short* dst = which2 ? B2s : B1s;
        int base = (u - (which2 ? P2n : 0)) * 8;
        int j0 = base & 31, c = (base >> 5) & 255, s = base >> 13;
        int k0 = s * 32 + j0;
        unsigned int pk[4];
        #pragma unroll
        for (int q = 0; q < 4; q++) {
            int ka = k0 + 2 * q, kb = ka + 1;
            float va = (ka < HID) ? root[(ka << 8) + c] : Wr[((ka - HID) << 8) + c];
            float vb = (kb < HID) ? root[(kb << 8) + c] : Wr[((kb - HID) << 8) + c];
            pk[q] = (unsigned int)f2bf(va) | ((unsigned int)f2bf(vb) << 16);
        }
        *(uint4*)&dst[base] = make_uint4(pk[0], pk[1], pk[2], pk[3]);
        return;
    }
    u -= 2 * P2n;
    if (u < PW2n) {
        // W2t[((s*8 + f)*64 + l)*8 + j] = bf16(W2[s*32 + (l>>4)*8 + j][f*16 + (l&15)])
        int s = u >> 9, f = (u >> 6) & 7, l = u & 63;
        int kb = s * 32 + ((l >> 4) << 3);
        int c  = (f << 4) + (l & 15);
        unsigned int pk[4];
        #pragma unroll
        for (int q = 0; q < 4; q++) {
            unsigned short lo = f2bf(W2[(size_t)(kb + 2 * q)     * OUT_DIM + c]);
            unsigned short hi = f2bf(W2[(size_t)(kb + 2 * q + 1) * OUT_DIM + c]);
            pk[q] = (unsigned int)lo | ((unsigned int)hi << 16);
        }
        *(uint4*)&W2t[(size_t)u * 8] = make_uint4(pk[0], pk[1], pk[2], pk[3]);
        return;
    }
    u -= PW2n;
    if (u < N_EDGES) {
        if (ei[N_EDGES + u] < BATCH) {
            need1[ei[u]] = 1;   // benign same-value race
            int p = atomicAdd(ectr2, 1);
            if (p < ECAP2) elist2[p] = u;
        }
    }
}

// ---------------- N2: mark0c + compact S1 (both depend only on need1) ----------------
__global__ void mark0_compact1(const int* __restrict__ ei, const int* __restrict__ need1,
                               int* __restrict__ need0,
                               int* __restrict__ elist1, int* __restrict__ ectr1,
                               int* __restrict__ idx1, int* __restrict__ map1,
                               int* __restrict__ n1ctr) {
    int t = blockIdx.x * blockDim.x + threadIdx.x;
    if (t < N_EDGES) {
        int d = ei[N_EDGES + t];
        if (d < BATCH || need1[d]) {
            need0[ei[t]] = 1;
            int p = atomicAdd(ectr1, 1);
            if (p < ECAP1) elist1[p] = t;
        }
        return;
    }
    int i = t - N_EDGES;
    if (i < N_NODES) {
        if ((i < BATCH) | need1[i]) {
            int p = atomicAdd(n1ctr, 1);
            if (p < CAP1) { idx1[p] = i; map1[i] = p; } else map1[i] = -1;
        } else map1[i] = -1;
    }
}

// ---------------- N3: compact S0 (needs need0 complete + map1) ----------------
__global__ void compact0(const int* __restrict__ map1, const int* __restrict__ need0,
                         int* __restrict__ idx0, int* __restrict__ map0,
                         int* __restrict__ n0ctr) {
    int i = blockIdx.x * blockDim.x + threadIdx.x;
    if (i >= N_NODES) return;
    if ((map1[i] >= 0) | need0[i]) {
        int p = atomicAdd(n0ctr, 1);
        if (p < CAP0) { idx0[p] = i; map0[i] = p; } else map0[i] = -1;
    } else map0[i] = -1;
}

// ---------------- scatter over compacted edge list (unchanged champion) ----------------
__global__ void scatter_c(const int* __restrict__ ei, const int* __restrict__ et,
                          const int* __restrict__ elist, const int* __restrict__ ectr, int ecap,
                          const int* __restrict__ mapSrc, const int* __restrict__ mapDst,
                          const float* __restrict__ hsrc,
                          float* __restrict__ Amsg, float* __restrict__ cnt,
                          int cntStride) {
    int g = blockIdx.x * blockDim.x + threadIdx.x;
    int ii = g >> 6, lane = g & 63;
    int n = imin(*ectr, ecap);
    if (ii >= n) return;
    int e = elist[ii];
    int d = ei[N_EDGES + e];
    int row = mapDst ? mapDst[d] : d;
    if (row < 0) return;
    int s = mapSrc[ei[e]];
    if (s < 0) return;
    int r = et[e];
    float4 v = *(const float4*)(hsrc + (size_t)s * HID + lane * 4);
    float* dp = Amsg + (size_t)row * MSGW + (size_t)r * HID + lane * 4;
    atomicAdd(dp + 0, v.x);
    atomicAdd(dp + 1, v.y);
    atomicAdd(dp + 2, v.z);
    atomicAdd(dp + 3, v.w);
    if (lane == 0) atomicAdd(cnt + (size_t)r * cntStride + row, 1.0f);
}

// ---------------- linear1 (unchanged champion) ----------------
__global__ __launch_bounds__(256) void gemm1_mfma(
    const float* __restrict__ x, const int* __restrict__ idx0,
    const unsigned short* __restrict__ w1s, const float* __restrict__ b1,
    float* __restrict__ h0c, const int* __restrict__ Mptr, int Mcap)
{
    int M = imin(*Mptr, Mcap);
    int bm = blockIdx.x * 64;
    if (bm >= M) return;

    __shared__ unsigned short As[64][40];
    __shared__ unsigned short Bs[256][40];

    int tid = threadIdx.x;
    int w = tid >> 6, lane = tid & 63;
    int l16 = lane & 15, lhi = lane >> 4;

    int ar = tid >> 2, ac = tid & 3;
    int gr = idx0[imin(bm + ar, M - 1)];
    const float* aptr = x + (size_t)gr * IN_DIM + ac * 8;

    f32x4 acc[16];
    #pragma unroll
    for (int i = 0; i < 16; i++) acc[i] = (f32x4)0.0f;

    for (int k0 = 0; k0 < IN_DIM; k0 += 32) {
        float4 a0 = *(const float4*)(aptr + k0);
        float4 a1 = *(const float4*)(aptr + k0 + 4);
        unsigned int p0 = (unsigned int)f2bf(a0.x) | ((unsigned int)f2bf(a0.y) << 16);
        unsigned int p1 = (unsigned int)f2bf(a0.z) | ((unsigned int)f2bf(a0.w) << 16);
        unsigned int p2 = (unsigned int)f2bf(a1.x) | ((unsigned int)f2bf(a1.y) << 16);
        unsigned int p3 = (unsigned int)f2bf(a1.z) | ((unsigned int)f2bf(a1.w) << 16);
        *(uint4*)&As[ar][ac * 8] = make_uint4(p0, p1, p2, p3);

        const uint4* bsrc = (const uint4*)(w1s + ((size_t)(k0 >> 5) * 256 + tid) * 32);
        int bswz = (tid >> 3) & 3;
        uint4 b0 = bsrc[0], b1v = bsrc[1], b2 = bsrc[2], b3 = bsrc[3];
        *(uint4*)&Bs[tid][(0 ^ bswz) * 8] = b0;
        *(uint4*)&Bs[tid][(1 ^ bswz) * 8] = b1v;
        *(uint4*)&Bs[tid][(2 ^ bswz) * 8] = b2;
        *(uint4*)&Bs[tid][(3 ^ bswz) * 8] = b3;
        __syncthreads();

        bf16x8 af = *(bf16x8*)&As[w * 16 + l16][lhi * 8];
        #pragma unroll
        for (int f = 0; f < 16; f++) {
            int col = f * 16 + l16;
            bf16x8 bf = *(bf16x8*)&Bs[col][(lhi ^ ((col >> 3) & 3)) * 8];
            acc[f] = __builtin_amdgcn_mfma_f32_16x16x32_bf16(af, bf, acc[f], 0, 0, 0);
        }
        __syncthreads();
    }

    #pragma unroll
    for (int f = 0; f < 16; f++) {
        int col = f * 16 + l16;
        float bb = b1[col];
        #pragma unroll
        for (int reg = 0; reg < 4; reg++) {
            int row = bm + w * 16 + lhi * 4 + reg;
            if (row < M) h0c[(size_t)row * HID + col] = fmaxf(acc[f][reg] + bb, 0.0f);
        }
    }
}

// ---------------- conv1 GEMM (unchanged champion) ----------------
__global__ __launch_bounds__(256) void conv_mfma(
    const float* __restrict__ hsrc,
    const int* __restrict__ idx, const int* __restrict__ map,
    const float* __restrict__ Amsg,
    const float* __restrict__ cnt, int cntStride,
    const unsigned short* __restrict__ Bt, const float* __restrict__ bias,
    float* __restrict__ Cout, const int* __restrict__ Mptr, int Mcap)
{
    int M = Mptr ? imin(*Mptr, Mcap) : Mcap;
    int bm = blockIdx.x * 64;
    if (bm >= M) return;

    __shared__ unsigned short As[64][40];
    __shared__ unsigned short Bs[256][40];

    int tid = threadIdx.x;
    int w = tid >> 6, lane = tid & 63;
    int l16 = lane & 15, lhi = lane >> 4;

    int ar = tid >> 2, ac = tid & 3;
    int row = imin(bm + ar, M - 1);
    int node = idx ? idx[row] : row;
    int grow = map[node]; if (grow < 0) grow = 0;
    const float* rootp = hsrc + (size_t)grow * HID + ac * 8;
    const float* msgp  = Amsg + (size_t)row * MSGW + ac * 8;
    float sc[NREL];
    #pragma unroll
    for (int r = 0; r < NREL; r++)
        sc[r] = 1.0f / fmaxf(cnt[(size_t)r * cntStride + row], 1.0f);

    f32x4 acc[16];
    #pragma unroll
    for (int i = 0; i < 16; i++) acc[i] = (f32x4)0.0f;

    for (int k0 = 0; k0 < KCAT; k0 += 32) {
        float4 a0, a1;
        if (k0 < HID) {
            a0 = *(const float4*)(rootp + k0);
            a1 = *(const float4*)(rootp + k0 + 4);
        } else {
            float s = sc[(k0 - HID) >> 8];
            a0 = *(const float4*)(msgp + (k0 - HID));
            a1 = *(const float4*)(msgp + (k0 - HID) + 4);
            a0.x *= s; a0.y *= s; a0.z *= s; a0.w *= s;
            a1.x *= s; a1.y *= s; a1.z *= s; a1.w *= s;
        }
        unsigned int p0 = (unsigned int)f2bf(a0.x) | ((unsigned int)f2bf(a0.y) << 16);
        unsigned int p1 = (unsigned int)f2bf(a0.z) | ((unsigned int)f2bf(a0.w) << 16);
        unsigned int p2 = (unsigned int)f2bf(a1.x) | ((unsigned int)f2bf(a1.y) << 16);
        unsigned int p3 = (unsigned int)f2bf(a1.z) | ((unsigned int)f2bf(a1.w) << 16);
        *(uint4*)&As[ar][ac * 8] = make_uint4(p0, p1, p2, p3);

        const uint4* bsrc = (const uint4*)(Bt + ((size_t)(k0 >> 5) * 256 + tid) * 32);
        int bswz = (tid >> 3) & 3;
        uint4 b0 = bsrc[0], b1v = bsrc[1], b2 = bsrc[2], b3 = bsrc[3];
        *(uint4*)&Bs[tid][(0 ^ bswz) * 8] = b0;
        *(uint4*)&Bs[tid][(1 ^ bswz) * 8] = b1v;
        *(uint4*)&Bs[tid][(2 ^ bswz) * 8] = b2;
        *(uint4*)&Bs[tid][(3 ^ bswz) * 8] = b3;
        __syncthreads();

        bf16x8 af = *(bf16x8*)&As[w * 16 + l16][lhi * 8];
        #pragma unroll
        for (int f = 0; f < 16; f++) {
            int col = f * 16 + l16;
            bf16x8 bf = *(bf16x8*)&Bs[col][(lhi ^ ((col >> 3) & 3)) * 8];
            acc[f] = __builtin_amdgcn_mfma_f32_16x16x32_bf16(af, bf, acc[f], 0, 0, 0);
        }
        __syncthreads();
    }

    #pragma unroll
    for (int f = 0; f < 16; f++) {
        int col = f * 16 + l16;
        float bb = bias[col];
        #pragma unroll
        for (int reg = 0; reg < 4; reg++) {
            int r = bm + w * 16 + lhi * 4 + reg;
            if (r < M) Cout[(size_t)r * HID + col] = acc[f][reg] + bb;
        }
    }
}

// ---------------- N8: conv2 + lin2 + relu + classifier, fused ----------------
// conv part identical to conv_mfma (idx=nullptr, M=BATCH). h2 tile (64x256)
// is block-local -> stage as bf16 in LDS, MFMA vs W2 fragments, classify.
__global__ __launch_bounds__(256) void conv2_fused(
    const float* __restrict__ hsrc, const int* __restrict__ map,
    const float* __restrict__ Amsg, const float* __restrict__ cnt,
    const unsigned short* __restrict__ Bt, const float* __restrict__ c2bias,
    const unsigned short* __restrict__ W2t, const float* __restrict__ b2,
    const float* __restrict__ Wc, const float* __restrict__ bc,
    float* __restrict__ out)
{
    int bm = blockIdx.x * 64;

    __shared__ unsigned short As[64][40];
    __shared__ unsigned short Bs[256][40];
    __shared__ unsigned short h2s[64][264];   // 256 cols + 8 pad (2-way banks)

    int tid = threadIdx.x;
    int w = tid >> 6, lane = tid & 63;
    int l16 = lane & 15, lhi = lane >> 4;

    int ar = tid >> 2, ac = tid & 3;
    int row = bm + ar;                         // always < BATCH
    int grow = map[row]; if (grow < 0) grow = 0;
    const float* rootp = hsrc + (size_t)grow * HID + ac * 8;
    const float* msgp  = Amsg + (size_t)row * MSGW + ac * 8;
    float sc[NREL];
    #pragma unroll
    for (int r = 0; r < NREL; r++)
        sc[r] = 1.0f / fmaxf(cnt[(size_t)r * BATCH + row], 1.0f);

    f32x4 acc[16];
    #pragma unroll
    for (int i = 0; i < 16; i++) acc[i] = (f32x4)0.0f;

    for (int k0 = 0; k0 < KCAT; k0 += 32) {
        float4 a0, a1;
        if (k0 < HID) {
            a0 = *(const float4*)(rootp + k0);
            a1 = *(const float4*)(rootp + k0 + 4);
        } else {
            float s = sc[(k0 - HID) >> 8];
            a0 = *(const float4*)(msgp + (k0 - HID));
            a1 = *(const float4*)(msgp + (k0 - HID) + 4);
            a0.x *= s; a0.y *= s; a0.z *= s; a0.w *= s;
            a1.x *= s; a1.y *= s; a1.z *= s; a1.w *= s;
        }
        unsigned int p0 = (unsigned int)f2bf(a0.x) | ((unsigned int)f2bf(a0.y) << 16);
        unsigned int p1 = (unsigned int)f2bf(a0.z) | ((unsigned int)f2bf(a0.w) << 16);
        unsigned int p2 = (unsigned int)f2bf(a1.x) | ((unsigned int)f2bf(a1.y) << 16);
        unsigned int p3 = (unsigned int)f2bf(a1.z) | ((unsigned int)f2bf(a1.w) << 16);
        *(uint4*)&As[ar][ac * 8] = make_uint4(p0, p1, p2, p3);

        const uint4* bsrc = (const uint4*)(Bt + ((size_t)(k0 >> 5) * 256 + tid) * 32);
        int bswz = (tid >> 3) & 3;
        uint4 b0 = bsrc[0], b1v = bsrc[1], b2v = bsrc[2], b3 = bsrc[3];
        *(uint4*)&Bs[tid][(0 ^ bswz) * 8] = b0;
        *(uint4*)&Bs[tid][(1 ^ bswz) * 8] = b1v;
        *(uint4*)&Bs[tid][(2 ^ bswz) * 8] = b2v;
        *(uint4*)&Bs[tid][(3 ^ bswz) * 8] = b3;
        __syncthreads();

        bf16x8 af = *(bf16x8*)&As[w * 16 + l16][lhi * 8];
        #pragma unroll
        for (int f = 0; f < 16; f++) {
            int col = f * 16 + l16;
            bf16x8 bf = *(bf16x8*)&Bs[col][(lhi ^ ((col >> 3) & 3)) * 8];
            acc[f] = __builtin_amdgcn_mfma_f32_16x16x32_bf16(af, bf, acc[f], 0, 0, 0);
        }
        __syncthreads();
    }

    // stage h2 tile (bias added, bf16) into LDS
    #pragma unroll
    for (int f = 0; f < 16; f++) {
        int col = f * 16 + l16;
        float bb = c2bias[col];
        #pragma unroll
        for (int reg = 0; reg < 4; reg++)
            h2s[w * 16 + lhi * 4 + reg][col] = f2bf(acc[f][reg] + bb);
    }
    __syncthreads();

    // lin2: h3 = relu(h2 @ W2 + b2)  -- 8 K-steps x 8 col-frags, MFMA
    f32x4 acc2[8];
    #pragma unroll
    for (int i = 0; i < 8; i++) acc2[i] = (f32x4)0.0f;
    for (int s = 0; s < 8; s++) {
        bf16x8 af = *(bf16x8*)&h2s[w * 16 + l16][s * 32 + lhi * 8];
        #pragma unroll
        for (int f = 0; f < 8; f++) {
            bf16x8 bf = *(const bf16x8*)(W2t + ((size_t)(s * 8 + f) * 64 + lane) * 8);
            acc2[f] = __builtin_amdgcn_mfma_f32_16x16x32_bf16(af, bf, acc2[f], 0, 0, 0);
        }
    }

    // classifier: logits[row] = sum_col relu(h3) * Wc + bc
    float p0[4] = {0.f, 0.f, 0.f, 0.f}, p1[4] = {0.f, 0.f, 0.f, 0.f};
    #pragma unroll
    for (int f = 0; f < 8; f++) {
        int col = f * 16 + l16;
        float w0 = Wc[col * 2 + 0], w1 = Wc[col * 2 + 1];
        float bb = b2[col];
        #pragma unroll
        for (int reg = 0; reg < 4; reg++) {
            float h = fmaxf(acc2[f][reg] + bb, 0.0f);
            p0[reg] += h * w0;
            p1[reg] += h * w1;
        }
    }
    #pragma unroll
    for (int o = 1; o <= 8; o <<= 1) {
        #pragma unroll
        for (int reg = 0; reg < 4; reg++) {
            p0[reg] += __shfl_xor(p0[reg], o);
            p1[reg] += __shfl_xor(p1[reg], o);
        }
    }
    if (l16 == 0) {
        #pragma unroll
        for (int reg = 0; reg < 4; reg++) {
            int r = bm + w * 16 + lhi * 4 + reg;
            out[r * 2 + 0] = p0[reg] + bc[0];
            out[r * 2 + 1] = p1[reg] + bc[1];
        }
    }
}

// ---------------- host ----------------

extern "C" void kernel_launch(void* const* d_in, const int* in_sizes, int n_in,
                              void* d_out, int out_size, void* d_ws, size_t ws_size,
                              hipStream_t stream) {
    const float* x      = (const float*)d_in[0];
    const int*   ei     = (const int*)d_in[1];
    const int*   et     = (const int*)d_in[2];
    const float* W1     = (const float*)d_in[4];
    const float* b1     = (const float*)d_in[5];
    const float* c1W    = (const float*)d_in[6];
    const float* c1root = (const float*)d_in[7];
    const float* c1bias = (const float*)d_in[8];
    const float* c2W    = (const float*)d_in[9];
    const float* c2root = (const float*)d_in[10];
    const float* c2bias = (const float*)d_in[11];
    const float* W2     = (const float*)d_in[12];
    const float* b2     = (const float*)d_in[13];
    const float* Wc     = (const float*)d_in[14];
    const float* bc     = (const float*)d_in[15];
    float* out = (float*)d_out;

    char* ws = (char*)d_ws;
    size_t off = 0;
    auto alloc = [&](size_t bytes) -> char* {
        char* p = ws + off;
        off = (off + bytes + 255) & ~(size_t)255;
        return p;
    };

    // --- memset region (node 0): ctrs | cnt1 | cnt2 | need1 | need0 ---
    size_t zb_ctr  = 16;
    size_t zb_cnt1 = (size_t)NREL * CAP1 * 4;
    size_t zb_cnt2 = (size_t)NREL * BATCH * 4;
    size_t zb_need = (size_t)N_NODES * 4;
    size_t msbytes = zb_ctr + zb_cnt1 + zb_cnt2 + 2 * zb_need;   // ~0.92 MB
    char* zsmall = alloc(msbytes);
    int*   n1ctr = (int*)zsmall;
    int*   n0ctr = n1ctr + 1;
    int*   ectr1 = n1ctr + 2;
    int*   ectr2 = n1ctr + 3;
    float* cnt1  = (float*)(zsmall + zb_ctr);
    float* cnt2  = (float*)(zsmall + zb_ctr + zb_cnt1);
    int*   need1 = (int*)(zsmall + zb_ctr + zb_cnt1 + zb_cnt2);
    int*   need0 = (int*)((char*)need1 + zb_need);

    // --- Amsg region (zeroed in N1) ---
    size_t zb_amsg1 = (size_t)CAP1 * MSGW * 4;
    size_t zb_amsg2 = (size_t)BATCH * MSGW * 4;
    char* amsg = alloc(zb_amsg1 + zb_amsg2);
    float* Amsg1 = (float*)amsg;
    float* Amsg2 = (float*)(amsg + zb_amsg1);
    int nzA = (int)((zb_amsg1 + zb_amsg2) / 16);

    int* map1  = (int*)alloc(N_NODES * 4);
    int* map0  = (int*)alloc(N_NODES * 4);
    int* idx1  = (int*)alloc(CAP1 * 4);
    int* idx0  = (int*)alloc(CAP0 * 4);
    int* elist1 = (int*)alloc(ECAP1 * 4);
    int* elist2 = (int*)alloc(ECAP2 * 4);
    float* h0c = (float*)alloc((size_t)CAP0 * HID * 4);
    float* h1c = (float*)alloc((size_t)CAP1 * HID * 4);
    unsigned short* w1s = (unsigned short*)alloc((size_t)IN_DIM * HID * 2);
    unsigned short* B1s = (unsigned short*)alloc((size_t)KCAT * HID * 2);
    unsigned short* B2s = (unsigned short*)alloc((size_t)KCAT * HID * 2);
    unsigned short* W2t = (unsigned short*)alloc((size_t)HID * OUT_DIM * 2);
    (void)ws_size; (void)in_sizes; (void)n_in; (void)out_size;

    const int NB = 256;

    // N0: zero flags/counters/cnts (small)
    hipMemsetAsync(zsmall, 0, msbytes, stream);
    // N1: Amsg zero + weight prep (w1s,B1s,B2s,W2t) + mark1c
    int n1_total = nzA + P1n + 2 * P2n + PW2n + N_EDGES;
    prep_mark1<<<dim3((n1_total + NB - 1) / NB), NB, 0, stream>>>(
        (uint4*)amsg, nzA, W1, c1root, c1W, c2root, c2W, W2,
        w1s, B1s, B2s, W2t, ei, need1, elist2, ectr2);
    // N2: mark0c + compact S1
    int n2_total = N_EDGES + N_NODES;
    mark0_compact1<<<dim3((n2_total + NB - 1) / NB), NB, 0, stream>>>(
        ei, need1, need0, elist1, ectr1, idx1, map1, n1ctr);
    // N3: compact S0
    compact0<<<dim3((N_NODES + NB - 1) / NB), NB, 0, stream>>>(map1, need0, idx0, map0, n0ctr);
    // N4: h0c = relu(x[S0] @ W1 + b1)
    gemm1_mfma<<<dim3(CAP0 / 64), NB, 0, stream>>>(x, idx0, w1s, b1, h0c, n0ctr, CAP0);
    // N5-N6: conv1
    scatter_c<<<dim3(ECAP1 * 64 / NB), NB, 0, stream>>>(ei, et, elist1, ectr1, ECAP1,
                                                        map0, map1, h0c, Amsg1, cnt1, CAP1);
    conv_mfma<<<dim3(CAP1 / 64), NB, 0, stream>>>(h0c, idx1, map0, Amsg1, cnt1, CAP1,
                                                  B1s, c1bias, h1c, n1ctr, CAP1);
    // N7: scatter for conv2
    scatter_c<<<dim3(ECAP2 * 64 / NB), NB, 0, stream>>>(ei, et, elist2, ectr2, ECAP2,
                                                        map1, nullptr, h1c, Amsg2, cnt2, BATCH);
    // N8: conv2 + lin2 + relu + classifier
    conv2_fused<<<dim3(BATCH / 64), NB, 0, stream>>>(h1c, map1, Amsg2, cnt2,
                                                     B2s, c2bias, W2t, b2, Wc, bc, out);
}